// Round 3
// baseline (920.659 us; speedup 1.0000x reference)
//
#include <hip/hip_runtime.h>
#include <hip/hip_bf16.h>

typedef __attribute__((ext_vector_type(8))) short short8;
typedef __attribute__((ext_vector_type(4))) float float4v;
typedef __attribute__((ext_vector_type(4))) int   int4v;

constexpr int NN = 2048;   // nodes
constexpr int TT = 4;      // time steps
constexpr int HH = 4;      // heads
constexpr int DD = 64;     // head dim
constexpr int THC = TT * HH;

__device__ __forceinline__ float bf2f(unsigned short u) {
    union { unsigned int i; float f; } c; c.i = ((unsigned int)u) << 16; return c.f;
}
__device__ __forceinline__ unsigned short f2bf(float f) {
    union { float f; unsigned int i; } c; c.f = f;
    unsigned int x = c.i;
    x += 0x7FFFu + ((x >> 16) & 1u);   // RNE
    return (unsigned short)(x >> 16);
}

// Mask dtype self-detect from first 1 KB (R6/R7-validated; pure fn of d_in).
// 0 = u8/bool, 1 = int32 0/1, 2 = f32, 3 = bf16.
__device__ __forceinline__ int mask_code_of(const unsigned int* mw) {
    int okInt = 1, okF32 = 1, okB = 1, anyLow = 0;
    for (int i = 0; i < 256; i++) {
        unsigned int w = mw[i];
        if (w > 1u) okInt = 0;
        if (!(w == 0u || w == 0x3F800000u)) okF32 = 0;
        unsigned int lo = w & 0xFFFFu, hi = w >> 16;
        if (!((lo == 0u || lo == 0x3F80u) && (hi == 0u || hi == 0x3F80u))) okB = 0;
        if (lo == 0x3F80u) anyLow = 1;
    }
    if (okInt) return 1;
    if (okF32 && !anyLow) return 2;
    if (okB) return 3;
    return 0;
}

// Vectorized nontemporal raw load of one 16-element mask slice, any dtype.
__device__ __forceinline__ void load_mask_raw(const void* p, size_t idx, int code,
                                              int4v mr[4]) {
    if (code == 1) {
        const int4v* mp = (const int4v*)((const int*)p + idx);
        #pragma unroll
        for (int q = 0; q < 4; q++) mr[q] = __builtin_nontemporal_load(mp + q);
    } else if (code == 2) {
        const int4v* mp = (const int4v*)((const float*)p + idx);
        #pragma unroll
        for (int q = 0; q < 4; q++) mr[q] = __builtin_nontemporal_load(mp + q);
    } else if (code == 3) {
        const int4v* mp = (const int4v*)((const unsigned short*)p + idx);
        mr[0] = __builtin_nontemporal_load(mp);
        mr[1] = __builtin_nontemporal_load(mp + 1);
    } else {  // u8/bool: 16 consecutive bytes, one dwordx4
        mr[0] = __builtin_nontemporal_load(
            (const int4v*)((const unsigned char*)p + idx));
    }
}
// Decode raw mask regs -> 16-bit predicate; bit k set iff element k is "true".
__device__ __forceinline__ unsigned decode_pm(const int4v mr[4], int code) {
    unsigned pm = 0u;
    if (code == 1) {
        #pragma unroll
        for (int q = 0; q < 4; q++)
            #pragma unroll
            for (int e = 0; e < 4; e++)
                if (mr[q][e] != 0) pm |= 1u << (q * 4 + e);
    } else if (code == 2) {
        #pragma unroll
        for (int q = 0; q < 4; q++)
            #pragma unroll
            for (int e = 0; e < 4; e++)
                if ((((unsigned)mr[q][e]) << 1) != 0u) pm |= 1u << (q * 4 + e);
    } else if (code == 3) {
        #pragma unroll
        for (int q = 0; q < 2; q++)
            #pragma unroll
            for (int e = 0; e < 4; e++) {
                unsigned w = (unsigned)mr[q][e];
                if (w & 0xFFFFu) pm |= 1u << (q * 8 + e * 2);
                if (w >> 16)     pm |= 1u << (q * 8 + e * 2 + 1);
            }
    } else {
        #pragma unroll
        for (int q = 0; q < 4; q++) {
            unsigned w = (unsigned)mr[0][q];
            #pragma unroll
            for (int b = 0; b < 4; b++)
                if ((w >> (8 * b)) & 0xFFu) pm |= 1u << (q * 4 + b);
        }
    }
    return pm;
}

// ---------------------------------------------------------------------------
// Kernel 1: projections, vectorized — unchanged (R6-validated FMA order).
// ---------------------------------------------------------------------------
constexpr int PROJ_ROWS = 8;
__global__ __launch_bounds__(256) void proj_b16v_kernel(
    const float* __restrict__ x,
    const float* __restrict__ Wq, const float* __restrict__ bq,
    const float* __restrict__ Wk, const float* __restrict__ bk,
    const float* __restrict__ Wv, const float* __restrict__ bv,
    unsigned short* __restrict__ q16, unsigned short* __restrict__ k16,
    unsigned short* __restrict__ v16)
{
    __shared__ float xl[PROJ_ROWS][64];
    const int tid = threadIdx.x;
    const int r0 = blockIdx.x * PROJ_ROWS;
    for (int i = tid; i < PROJ_ROWS * 64; i += 256)
        xl[i >> 6][i & 63] = x[(size_t)r0 * 64 + i];
    __syncthreads();

    const int c = tid;
    const int hh = c >> 6, dd = c & 63;
    const float* Ws[3] = { Wq, Wk, Wv };
    const float* bs[3] = { bq, bk, bv };
    unsigned short* os[3] = { q16, k16, v16 };

    #pragma unroll
    for (int m = 0; m < 3; m++) {
        float4v wr4[16];
        #pragma unroll
        for (int i = 0; i < 16; i++)
            wr4[i] = *(const float4v*)&Ws[m][(size_t)c * 64 + i * 4];
        const float bias = bs[m][c];
        #pragma unroll
        for (int rr = 0; rr < PROJ_ROWS; rr++) {
            float a = bias;
            #pragma unroll
            for (int i = 0; i < 16; i++) {
                a = fmaf(wr4[i][0], xl[rr][4*i+0], a);
                a = fmaf(wr4[i][1], xl[rr][4*i+1], a);
                a = fmaf(wr4[i][2], xl[rr][4*i+2], a);
                a = fmaf(wr4[i][3], xl[rr][4*i+3], a);
            }
            if (m == 0) a *= 0.125f;
            const int r = r0 + rr;
            const int n = r >> 2, t = r & 3;
            const int th = t * HH + hh;
            os[m][((size_t)th * NN + n) * DD + dd] = f2bf(a);
        }
    }
}

// ---------------------------------------------------------------------------
// Kernel 1b: one-time V transpose  v16[th][n][d] -> v16t[th][d][n].
// ---------------------------------------------------------------------------
__global__ __launch_bounds__(256) void vtrans_kernel(
    const unsigned short* __restrict__ v16, unsigned short* __restrict__ v16t)
{
    __shared__ unsigned int Tl[64][65];
    const int tid = threadIdx.x;
    const int th = blockIdx.x >> 5;           // 0..15
    const int n0 = (blockIdx.x & 31) * 64;    // 0..2047 step 64
    const unsigned short* src = v16 + ((size_t)th * NN + n0) * DD;
    {
        const int r = tid >> 2, c0 = (tid & 3) * 16;
        short8 a0 = *(const short8*)&src[(size_t)r * DD + c0];
        short8 a1 = *(const short8*)&src[(size_t)r * DD + c0 + 8];
        #pragma unroll
        for (int e = 0; e < 8; e++) {
            Tl[r][c0 + e]     = (unsigned short)a0[e];
            Tl[r][c0 + 8 + e] = (unsigned short)a1[e];
        }
    }
    __syncthreads();
    {
        const int dr = tid >> 2, c0 = (tid & 3) * 16;
        alignas(16) unsigned short tmp[16];
        #pragma unroll
        for (int j = 0; j < 16; j++) tmp[j] = (unsigned short)Tl[c0 + j][dr];
        unsigned short* dst = v16t + ((size_t)th * DD + dr) * NN + n0 + c0;
        *(short8*)&dst[0] = *(const short8*)&tmp[0];
        *(short8*)&dst[8] = *(const short8*)&tmp[8];
    }
}

// ---------------------------------------------------------------------------
// Kernel 2: MFMA flash attention v5 — KV-SPLIT x4 for full occupancy.
// Block = one 16-row q-tile, 4 waves; wave w covers kv in [w*512, w*512+512).
// Grid 2048 x 256 thr = 8192 waves = 32 waves/CU (whole grid co-resident at
// 8 blocks/CU: LDS 18.4 KB/block, launch_bounds(256,8) pins VGPR <= 64).
// Per-wave loop body is byte-identical to the R7-validated math; K/V frags
// read direct from L2 (512 KB/th working set), merged PV, NT watt/mask.
// Per-wave LDS scratch (4608 B) aliases Sl(f32) with PlR/PlW(bf16) — Sl is
// fully consumed into s4 regs before P is produced; compiler memory fences
// at iteration top + barriers at the epilogue prevent TBAA reordering.
// Final cross-wave flash merge (m*=max, o*=sum e^{m_w-m*} o_w, l*=likewise)
// runs through the same scratch, one path at a time.
// mfma_f32_16x16x32_bf16: A lane(row=l&15,k=(l>>4)*8+e),
// B lane(col=l&15,k=(l>>4)*8+e), D lane(col=l&15,row=(l>>4)*4+reg).
// ---------------------------------------------------------------------------
constexpr int SCR = 4608;   // per-wave scratch bytes
__global__ __launch_bounds__(256, 8) void attn_mfma5_kernel(
    const unsigned short* __restrict__ q16, const unsigned short* __restrict__ k16,
    const unsigned short* __restrict__ v16t,
    const float* __restrict__ watt, const void* __restrict__ maskp,
    float* __restrict__ out, float* __restrict__ out_raw)
{
    const int code = mask_code_of((const unsigned int*)maskp);
    const int tid  = threadIdx.x;
    const int w    = tid >> 6;          // wave 0..3 = KV quarter
    const int lane = tid & 63;
    const int g    = lane >> 4;         // MFMA 16-lane group
    const int j0   = lane & 15;
    const int lr   = lane >> 2;         // remap: row 0..15
    const int lc   = lane & 3;          // remap: col quarter 0..3

    const int gid = blockIdx.x;         // 0..2047
    const int th  = gid & 15;           // XCD x hosts th in {x, x+8}: L2-local
    const int bx  = gid >> 4;           // 0..127
    const int t = th >> 2, h = th & 3;
    const int row0 = bx * 16;

    const unsigned short* Qb  = q16  + (size_t)th * NN * DD;
    const unsigned short* Kb  = k16  + (size_t)th * NN * DD;
    const unsigned short* Vtb = v16t + (size_t)th * DD * NN;

    __shared__ __align__(16) char smem[4 * SCR];
    char* scw = smem + w * SCR;
    float*          Slp  = (float*)scw;                  // [16][68] f32
    unsigned short* PlRp = (unsigned short*)scw;         // [16][72] bf16
    unsigned short* PlWp = (unsigned short*)(scw + 2304);// [16][72] bf16

    short8 aq0, aq1;   // Q A-fragments
    {
        const unsigned short* qp = Qb + (size_t)(row0 + j0) * DD + g * 8;
        aq0 = *(const short8*)qp;
        aq1 = *(const short8*)(qp + 32);
    }

    float m_r = -1e30f, l_r = 0.f, m_w = -1e30f, l_w = 0.f;
    float4v o_r[4], o_w[4];
    #pragma unroll
    for (int ns = 0; ns < 4; ns++) {
        o_r[ns] = (float4v){0.f, 0.f, 0.f, 0.f};
        o_w[ns] = (float4v){0.f, 0.f, 0.f, 0.f};
    }

    const size_t mrow = ((size_t)th * NN + row0 + lr) * NN;  // watt/mask row base

    const int kv_beg = w * (NN / 4);
    const int kv_end = kv_beg + (NN / 4);

    for (int kv0 = kv_beg; kv0 < kv_end; kv0 += 64) {
        // fence: prev-iter PV short8 reads must not sink past this iter's
        // Sl float stores (aliased bytes, different TBAA types)
        asm volatile("" ::: "memory");

        // ---- watt/mask NT loads (consumed after QK^T + raw path) ----
        float4v wv4[4];
        int4v   mk4[4];
        {
            const float* wp = watt + mrow + kv0 + lc * 16;
            #pragma unroll
            for (int q = 0; q < 4; q++)
                wv4[q] = __builtin_nontemporal_load((const float4v*)&wp[q * 4]);
            load_mask_raw(maskp, mrow + kv0 + lc * 16, code, mk4);
        }

        // ---- QK^T, K-frags direct from L2: acc[c][i]=S[row0+4g+i][kv0+16c+j0]
        float4v acc[4];
        #pragma unroll
        for (int c = 0; c < 4; c++) {
            const unsigned short* kp = Kb + (size_t)(kv0 + c * 16 + j0) * DD + g * 8;
            short8 b0 = *(const short8*)kp;
            short8 b1 = *(const short8*)(kp + 32);
            float4v z = (float4v){0.f, 0.f, 0.f, 0.f};
            z = __builtin_amdgcn_mfma_f32_16x16x32_bf16(aq0, b0, z, 0, 0, 0);
            z = __builtin_amdgcn_mfma_f32_16x16x32_bf16(aq1, b1, z, 0, 0, 0);
            acc[c] = z;
        }
        // scatter S to LDS, re-read in remap arrangement (wave-local, in-order)
        #pragma unroll
        for (int c = 0; c < 4; c++)
            #pragma unroll
            for (int i = 0; i < 4; i++)
                Slp[(g * 4 + i) * 68 + c * 16 + j0] = acc[c][i];
        float4v s4[4];
        #pragma unroll
        for (int q = 0; q < 4; q++)
            s4[q] = *(const float4v*)&Slp[lr * 68 + lc * 16 + q * 4];

        // ---------------- raw path softmax ----------------
        {
            float tmax = -3.0e38f;
            #pragma unroll
            for (int q = 0; q < 4; q++)
                #pragma unroll
                for (int e = 0; e < 4; e++) tmax = fmaxf(tmax, s4[q][e]);
            tmax = fmaxf(tmax, __shfl_xor(tmax, 1, 64));
            tmax = fmaxf(tmax, __shfl_xor(tmax, 2, 64));
            float mn = fmaxf(m_r, tmax);
            float alpha = __expf(m_r - mn);
            m_r = mn;
            alignas(16) unsigned short pb[16];
            float tsum = 0.f;
            #pragma unroll
            for (int q = 0; q < 4; q++)
                #pragma unroll
                for (int e = 0; e < 4; e++) {
                    unsigned short b = f2bf(__expf(s4[q][e] - mn));
                    pb[q * 4 + e] = b; tsum += bf2f(b);
                }
            tsum += __shfl_xor(tsum, 1, 64);
            tsum += __shfl_xor(tsum, 2, 64);
            l_r = l_r * alpha + tsum;
            *(short8*)&PlRp[lr * 72 + lc * 16]     = *(const short8*)&pb[0];
            *(short8*)&PlRp[lr * 72 + lc * 16 + 8] = *(const short8*)&pb[8];
            float aR[4];
            #pragma unroll
            for (int i = 0; i < 4; i++) aR[i] = __shfl(alpha, (g * 4 + i) * 4, 64);
            #pragma unroll
            for (int ns = 0; ns < 4; ns++)
                #pragma unroll
                for (int i = 0; i < 4; i++) o_r[ns][i] *= aR[i];
        }

        // ---------------- weighted + masked path softmax ----------------
        {
            const unsigned pm = decode_pm(mk4, code);
            float sw[16];
            #pragma unroll
            for (int q = 0; q < 4; q++)
                #pragma unroll
                for (int e = 0; e < 4; e++) {
                    const int k = q * 4 + e;
                    sw[k] = ((pm >> k) & 1u) ? -1e30f : s4[q][e] * wv4[q][e];
                }
            float tmax = -3.0e38f;
            #pragma unroll
            for (int k = 0; k < 16; k++) tmax = fmaxf(tmax, sw[k]);
            tmax = fmaxf(tmax, __shfl_xor(tmax, 1, 64));
            tmax = fmaxf(tmax, __shfl_xor(tmax, 2, 64));
            float mn = fmaxf(m_w, tmax);
            float alpha = __expf(m_w - mn);
            m_w = mn;
            alignas(16) unsigned short pb[16];
            float tsum = 0.f;
            #pragma unroll
            for (int k = 0; k < 16; k++) {
                unsigned short b = f2bf(__expf(sw[k] - mn));
                pb[k] = b; tsum += bf2f(b);
            }
            tsum += __shfl_xor(tsum, 1, 64);
            tsum += __shfl_xor(tsum, 2, 64);
            l_w = l_w * alpha + tsum;
            *(short8*)&PlWp[lr * 72 + lc * 16]     = *(const short8*)&pb[0];
            *(short8*)&PlWp[lr * 72 + lc * 16 + 8] = *(const short8*)&pb[8];
            float aW[4];
            #pragma unroll
            for (int i = 0; i < 4; i++) aW[i] = __shfl(alpha, (g * 4 + i) * 4, 64);
            #pragma unroll
            for (int ns = 0; ns < 4; ns++)
                #pragma unroll
                for (int i = 0; i < 4; i++) o_w[ns][i] *= aW[i];
        }

        // ---- merged PV: each V fragment (from L2) feeds both paths ----
        #pragma unroll
        for (int ks2 = 0; ks2 < 2; ks2++) {
            short8 paR = *(const short8*)&PlRp[j0 * 72 + ks2 * 32 + g * 8];
            short8 paW = *(const short8*)&PlWp[j0 * 72 + ks2 * 32 + g * 8];
            #pragma unroll
            for (int ns = 0; ns < 4; ns++) {
                const unsigned short* vp =
                    Vtb + (size_t)(ns * 16 + j0) * NN + kv0 + ks2 * 32 + g * 8;
                short8 vb8 = *(const short8*)vp;
                o_r[ns] = __builtin_amdgcn_mfma_f32_16x16x32_bf16(paR, vb8, o_r[ns], 0, 0, 0);
                o_w[ns] = __builtin_amdgcn_mfma_f32_16x16x32_bf16(paW, vb8, o_w[ns], 0, 0, 0);
            }
        }
    }

    // =================== cross-wave flash merge epilogue ===================
    // Scratch per wave: o[16][64] f32 @0 (4096B), m[16] @4096, l[16] @4160.
    __syncthreads();   // B0: all PV scratch reads done; also fences aliasing

    // ---- path RAW ----
    {
        float* ov = (float*)scw;
        #pragma unroll
        for (int ns = 0; ns < 4; ns++)
            #pragma unroll
            for (int i = 0; i < 4; i++)
                ov[(g * 4 + i) * 64 + ns * 16 + j0] = o_r[ns][i];
        if (lc == 0) {
            *(float*)(scw + 4096 + lr * 4) = m_r;
            *(float*)(scw + 4160 + lr * 4) = l_r;
        }
    }
    __syncthreads();   // B1
    {
        const int r  = tid >> 4;          // 0..15
        const int c0 = (tid & 15) * 4;    // 0..60
        float mv[4];
        float M = -3.0e38f;
        #pragma unroll
        for (int u = 0; u < 4; u++) {
            mv[u] = *(const float*)(smem + u * SCR + 4096 + r * 4);
            M = fmaxf(M, mv[u]);
        }
        float L = 0.f;
        float4v a = (float4v){0.f, 0.f, 0.f, 0.f};
        #pragma unroll
        for (int u = 0; u < 4; u++) {
            const float f = __expf(mv[u] - M);
            L += f * *(const float*)(smem + u * SCR + 4160 + r * 4);
            float4v o4 = *(const float4v*)(smem + u * SCR + r * 256 + c0 * 4);
            #pragma unroll
            for (int e = 0; e < 4; e++) a[e] = fmaf(f, o4[e], a[e]);
        }
        const int row = row0 + r;
        const size_t ob = (((size_t)h * NN + row) * TT + t) * DD + c0;
        const float inv = 1.0f / L;
        float4v res = { a[0] * inv, a[1] * inv, a[2] * inv, a[3] * inv };
        *(float4v*)&out_raw[ob] = res;
    }
    __syncthreads();   // B2

    // ---- path WEIGHTED ----
    {
        float* ov = (float*)scw;
        #pragma unroll
        for (int ns = 0; ns < 4; ns++)
            #pragma unroll
            for (int i = 0; i < 4; i++)
                ov[(g * 4 + i) * 64 + ns * 16 + j0] = o_w[ns][i];
        if (lc == 0) {
            *(float*)(scw + 4096 + lr * 4) = m_w;
            *(float*)(scw + 4160 + lr * 4) = l_w;
        }
    }
    __syncthreads();   // B3
    {
        const int r  = tid >> 4;
        const int c0 = (tid & 15) * 4;
        float mv[4];
        float M = -3.0e38f;
        #pragma unroll
        for (int u = 0; u < 4; u++) {
            mv[u] = *(const float*)(smem + u * SCR + 4096 + r * 4);
            M = fmaxf(M, mv[u]);
        }
        float L = 0.f;
        float4v a = (float4v){0.f, 0.f, 0.f, 0.f};
        #pragma unroll
        for (int u = 0; u < 4; u++) {
            const float f = __expf(mv[u] - M);
            L += f * *(const float*)(smem + u * SCR + 4160 + r * 4);
            float4v o4 = *(const float4v*)(smem + u * SCR + r * 256 + c0 * 4);
            #pragma unroll
            for (int e = 0; e < 4; e++) a[e] = fmaf(f, o4[e], a[e]);
        }
        const int row = row0 + r;
        const size_t ob = (((size_t)h * NN + row) * TT + t) * DD + c0;
        const float inv = 1.0f / L;
        float4v res = { a[0] * inv, a[1] * inv, a[2] * inv, a[3] * inv };
        *(float4v*)&out[ob] = res;
    }
}

// ---------------------------------------------------------------------------
// Kernel 3: raw_att[t=3,h=0] slice — unchanged (R7-validated).
// ---------------------------------------------------------------------------
__global__ __launch_bounds__(256) void slice_b16_kernel(
    const unsigned short* __restrict__ q16, const unsigned short* __restrict__ k16,
    float* __restrict__ out_sl)
{
    const int tid = threadIdx.x;
    const int w = tid >> 6, lane = tid & 63;
    const int thsel = 12;  // t=3, h=0
    const unsigned short* Kb = k16 + (size_t)thsel * NN * DD;

    __shared__ float Tt[64][65];
    __shared__ float sr[4][NN];
    __shared__ float ql[4][64];

    ql[tid >> 6][tid & 63] =
        bf2f(q16[((size_t)thsel * NN + blockIdx.x * 4 + (tid >> 6))* DD + (tid & 63)]);
    __syncthreads();
    float qr[64];
    #pragma unroll
    for (int d = 0; d < 64; d++) qr[d] = ql[w][d];

    for (int kt = 0; kt < NN / 64; ++kt) {
        __syncthreads();
        const unsigned short* Ks = Kb + (size_t)kt * 64 * DD;
        #pragma unroll
        for (int u = 0; u < 16; ++u) {
            int e = u * 256 + tid;
            Tt[e >> 6][e & 63] = bf2f(Ks[e]);
        }
        __syncthreads();
        float a = 0.f;
        #pragma unroll
        for (int d = 0; d < 64; ++d)
            a = fmaf(qr[d], Tt[lane][d], a);
        sr[w][kt * 64 + lane] = a;
    }

    const int r = blockIdx.x * 4 + w;
    float mx = -3.0e38f;
    for (int m = lane; m < NN; m += 64) mx = fmaxf(mx, sr[w][m]);
    #pragma unroll
    for (int o = 1; o < 64; o <<= 1) mx = fmaxf(mx, __shfl_xor(mx, o, 64));
    float se = 0.f;
    for (int m = lane; m < NN; m += 64) se += __expf(sr[w][m] - mx);
    #pragma unroll
    for (int o = 1; o < 64; o <<= 1) se += __shfl_xor(se, o, 64);
    const float inv = 1.0f / se;
    for (int m = lane; m < NN; m += 64)
        out_sl[(size_t)r * NN + m] = __expf(sr[w][m] - mx) * inv;
}

// ---------------------------------------------------------------------------
extern "C" void kernel_launch(void* const* d_in, const int* in_sizes, int n_in,
                              void* d_out, int out_size, void* d_ws, size_t ws_size,
                              hipStream_t stream)
{
    (void)in_sizes; (void)n_in; (void)out_size; (void)ws_size;
    const float* x    = (const float*)d_in[0];
    const float* Wq   = (const float*)d_in[1];
    const float* bq   = (const float*)d_in[2];
    const float* Wk   = (const float*)d_in[3];
    const float* bk   = (const float*)d_in[4];
    const float* Wv   = (const float*)d_in[5];
    const float* bv   = (const float*)d_in[6];
    const float* watt = (const float*)d_in[7];
    const void*  mask = d_in[8];

    unsigned short* q16 = (unsigned short*)d_ws;              // 4 MB
    unsigned short* k16 = q16 + (size_t)THC * NN * DD;        // +4 MB
    unsigned short* v16 = k16 + (size_t)THC * NN * DD;        // +4 MB (12 MB)

    float* out     = (float*)d_out;
    float* out_raw = out + (size_t)NN * TT * HH * DD;
    float* out_sl  = out + 2 * (size_t)NN * TT * HH * DD;

    // v16t (4 MB) lives in the out_sl region as scratch: attn reads it, then
    // slice_b16_kernel fully overwrites out_sl afterwards.
    unsigned short* v16t = (unsigned short*)out_sl;

    proj_b16v_kernel<<<NN * TT / PROJ_ROWS, 256, 0, stream>>>(
        x, Wq, bq, Wk, bk, Wv, bv, q16, k16, v16);
    vtrans_kernel<<<THC * (NN / 64), 256, 0, stream>>>(v16, v16t);
    attn_mfma5_kernel<<<(NN / 16) * THC, 256, 0, stream>>>(
        q16, k16, v16t, watt, mask, out, out_raw);
    slice_b16_kernel<<<NN / 4, 256, 0, stream>>>(q16, k16, out_sl);
}

// Round 4
// 424.568 us; speedup vs baseline: 2.1685x; 2.1685x over previous
//
#include <hip/hip_runtime.h>
#include <hip/hip_bf16.h>

typedef __attribute__((ext_vector_type(8))) short short8;
typedef __attribute__((ext_vector_type(4))) float float4v;
typedef __attribute__((ext_vector_type(4))) int   int4v;

constexpr int NN = 2048;   // nodes
constexpr int TT = 4;      // time steps
constexpr int HH = 4;      // heads
constexpr int DD = 64;     // head dim
constexpr int THC = TT * HH;

__device__ __forceinline__ float bf2f(unsigned short u) {
    union { unsigned int i; float f; } c; c.i = ((unsigned int)u) << 16; return c.f;
}
__device__ __forceinline__ unsigned short f2bf(float f) {
    union { float f; unsigned int i; } c; c.f = f;
    unsigned int x = c.i;
    x += 0x7FFFu + ((x >> 16) & 1u);   // RNE
    return (unsigned short)(x >> 16);
}

// Mask dtype self-detect from first 1 KB (R6/R7-validated; pure fn of d_in).
// 0 = u8/bool, 1 = int32 0/1, 2 = f32, 3 = bf16.
__device__ __forceinline__ int mask_code_of(const unsigned int* mw) {
    int okInt = 1, okF32 = 1, okB = 1, anyLow = 0;
    for (int i = 0; i < 256; i++) {
        unsigned int w = mw[i];
        if (w > 1u) okInt = 0;
        if (!(w == 0u || w == 0x3F800000u)) okF32 = 0;
        unsigned int lo = w & 0xFFFFu, hi = w >> 16;
        if (!((lo == 0u || lo == 0x3F80u) && (hi == 0u || hi == 0x3F80u))) okB = 0;
        if (lo == 0x3F80u) anyLow = 1;
    }
    if (okInt) return 1;
    if (okF32 && !anyLow) return 2;
    if (okB) return 3;
    return 0;
}

// Vectorized nontemporal raw load of one 16-element mask slice, any dtype.
__device__ __forceinline__ void load_mask_raw(const void* p, size_t idx, int code,
                                              int4v mr[4]) {
    if (code == 1) {
        const int4v* mp = (const int4v*)((const int*)p + idx);
        #pragma unroll
        for (int q = 0; q < 4; q++) mr[q] = __builtin_nontemporal_load(mp + q);
    } else if (code == 2) {
        const int4v* mp = (const int4v*)((const float*)p + idx);
        #pragma unroll
        for (int q = 0; q < 4; q++) mr[q] = __builtin_nontemporal_load(mp + q);
    } else if (code == 3) {
        const int4v* mp = (const int4v*)((const unsigned short*)p + idx);
        mr[0] = __builtin_nontemporal_load(mp);
        mr[1] = __builtin_nontemporal_load(mp + 1);
    } else {  // u8/bool: 16 consecutive bytes, one dwordx4
        mr[0] = __builtin_nontemporal_load(
            (const int4v*)((const unsigned char*)p + idx));
    }
}
// Decode raw mask regs -> 16-bit predicate; bit k set iff element k is "true".
__device__ __forceinline__ unsigned decode_pm(const int4v mr[4], int code) {
    unsigned pm = 0u;
    if (code == 1) {
        #pragma unroll
        for (int q = 0; q < 4; q++)
            #pragma unroll
            for (int e = 0; e < 4; e++)
                if (mr[q][e] != 0) pm |= 1u << (q * 4 + e);
    } else if (code == 2) {
        #pragma unroll
        for (int q = 0; q < 4; q++)
            #pragma unroll
            for (int e = 0; e < 4; e++)
                if ((((unsigned)mr[q][e]) << 1) != 0u) pm |= 1u << (q * 4 + e);
    } else if (code == 3) {
        #pragma unroll
        for (int q = 0; q < 2; q++)
            #pragma unroll
            for (int e = 0; e < 4; e++) {
                unsigned w = (unsigned)mr[q][e];
                if (w & 0xFFFFu) pm |= 1u << (q * 8 + e * 2);
                if (w >> 16)     pm |= 1u << (q * 8 + e * 2 + 1);
            }
    } else {
        #pragma unroll
        for (int q = 0; q < 4; q++) {
            unsigned w = (unsigned)mr[0][q];
            #pragma unroll
            for (int b = 0; b < 4; b++)
                if ((w >> (8 * b)) & 0xFFu) pm |= 1u << (q * 4 + b);
        }
    }
    return pm;
}

// ---------------------------------------------------------------------------
// Kernel 1: projections, vectorized — unchanged (R6-validated FMA order).
// ---------------------------------------------------------------------------
constexpr int PROJ_ROWS = 8;
__global__ __launch_bounds__(256) void proj_b16v_kernel(
    const float* __restrict__ x,
    const float* __restrict__ Wq, const float* __restrict__ bq,
    const float* __restrict__ Wk, const float* __restrict__ bk,
    const float* __restrict__ Wv, const float* __restrict__ bv,
    unsigned short* __restrict__ q16, unsigned short* __restrict__ k16,
    unsigned short* __restrict__ v16)
{
    __shared__ float xl[PROJ_ROWS][64];
    const int tid = threadIdx.x;
    const int r0 = blockIdx.x * PROJ_ROWS;
    for (int i = tid; i < PROJ_ROWS * 64; i += 256)
        xl[i >> 6][i & 63] = x[(size_t)r0 * 64 + i];
    __syncthreads();

    const int c = tid;
    const int hh = c >> 6, dd = c & 63;
    const float* Ws[3] = { Wq, Wk, Wv };
    const float* bs[3] = { bq, bk, bv };
    unsigned short* os[3] = { q16, k16, v16 };

    #pragma unroll
    for (int m = 0; m < 3; m++) {
        float4v wr4[16];
        #pragma unroll
        for (int i = 0; i < 16; i++)
            wr4[i] = *(const float4v*)&Ws[m][(size_t)c * 64 + i * 4];
        const float bias = bs[m][c];
        #pragma unroll
        for (int rr = 0; rr < PROJ_ROWS; rr++) {
            float a = bias;
            #pragma unroll
            for (int i = 0; i < 16; i++) {
                a = fmaf(wr4[i][0], xl[rr][4*i+0], a);
                a = fmaf(wr4[i][1], xl[rr][4*i+1], a);
                a = fmaf(wr4[i][2], xl[rr][4*i+2], a);
                a = fmaf(wr4[i][3], xl[rr][4*i+3], a);
            }
            if (m == 0) a *= 0.125f;
            const int r = r0 + rr;
            const int n = r >> 2, t = r & 3;
            const int th = t * HH + hh;
            os[m][((size_t)th * NN + n) * DD + dd] = f2bf(a);
        }
    }
}

// ---------------------------------------------------------------------------
// Kernel 1b: one-time V transpose  v16[th][n][d] -> v16t[th][d][n].
// ---------------------------------------------------------------------------
__global__ __launch_bounds__(256) void vtrans_kernel(
    const unsigned short* __restrict__ v16, unsigned short* __restrict__ v16t)
{
    __shared__ unsigned int Tl[64][65];
    const int tid = threadIdx.x;
    const int th = blockIdx.x >> 5;           // 0..15
    const int n0 = (blockIdx.x & 31) * 64;    // 0..2047 step 64
    const unsigned short* src = v16 + ((size_t)th * NN + n0) * DD;
    {
        const int r = tid >> 2, c0 = (tid & 3) * 16;
        short8 a0 = *(const short8*)&src[(size_t)r * DD + c0];
        short8 a1 = *(const short8*)&src[(size_t)r * DD + c0 + 8];
        #pragma unroll
        for (int e = 0; e < 8; e++) {
            Tl[r][c0 + e]     = (unsigned short)a0[e];
            Tl[r][c0 + 8 + e] = (unsigned short)a1[e];
        }
    }
    __syncthreads();
    {
        const int dr = tid >> 2, c0 = (tid & 3) * 16;
        alignas(16) unsigned short tmp[16];
        #pragma unroll
        for (int j = 0; j < 16; j++) tmp[j] = (unsigned short)Tl[c0 + j][dr];
        unsigned short* dst = v16t + ((size_t)th * DD + dr) * NN + n0 + c0;
        *(short8*)&dst[0] = *(const short8*)&tmp[0];
        *(short8*)&dst[8] = *(const short8*)&tmp[8];
    }
}

// ---------------------------------------------------------------------------
// Kernel 2: MFMA flash attention v6 — KV-SPLIT x4, spill-free register budget.
// Block = one 16-row q-tile, 4 waves; wave w covers kv in [w*512, w*512+512).
// Grid 2048 x 256 thr. launch_bounds(256,4): 128 VGPR cap (body needs ~100,
// R3's (256,8)=64-cap spilled ~1.1 GB scratch traffic — the R3 lesson).
// 4 blocks/CU x 4 waves = 16 waves/CU; LDS 35.8 KB/block x 4 = 143 KB/CU.
// Per-wave scratch regions are DISJOINT (Sl no longer aliases PlR/PlW), so
// no compiler memory fences are needed — global loads (watt/mask/K/V, which
// never alias LDS) are free to hoist across iterations (compiler pipelining).
// Per-wave loop body math is byte-identical to the R7-validated kernel; K/V
// frags read direct from L2 (512 KB per th), merged PV, NT watt/mask loads.
// Cross-wave flash merge epilogue (validated in R3) through the Sl region.
// mfma_f32_16x16x32_bf16: A lane(row=l&15,k=(l>>4)*8+e),
// B lane(col=l&15,k=(l>>4)*8+e), D lane(col=l&15,row=(l>>4)*4+reg).
// ---------------------------------------------------------------------------
constexpr int SCR = 8960;   // per-wave scratch bytes: Sl 4352 | PlR 2304 | PlW 2304
__global__ __launch_bounds__(256, 4) void attn_mfma6_kernel(
    const unsigned short* __restrict__ q16, const unsigned short* __restrict__ k16,
    const unsigned short* __restrict__ v16t,
    const float* __restrict__ watt, const void* __restrict__ maskp,
    float* __restrict__ out, float* __restrict__ out_raw)
{
    const int code = mask_code_of((const unsigned int*)maskp);
    const int tid  = threadIdx.x;
    const int w    = tid >> 6;          // wave 0..3 = KV quarter
    const int lane = tid & 63;
    const int g    = lane >> 4;         // MFMA 16-lane group
    const int j0   = lane & 15;
    const int lr   = lane >> 2;         // remap: row 0..15
    const int lc   = lane & 3;          // remap: col quarter 0..3

    const int gid = blockIdx.x;         // 0..2047
    const int th  = gid & 15;           // XCD x hosts th in {x, x+8}: L2-local
    const int bx  = gid >> 4;           // 0..127
    const int t = th >> 2, h = th & 3;
    const int row0 = bx * 16;

    const unsigned short* Qb  = q16  + (size_t)th * NN * DD;
    const unsigned short* Kb  = k16  + (size_t)th * NN * DD;
    const unsigned short* Vtb = v16t + (size_t)th * DD * NN;

    __shared__ __align__(16) char smem[4 * SCR];
    char* scw = smem + w * SCR;
    float*          Slp  = (float*)scw;                  // [16][68] f32 (4352 B)
    unsigned short* PlRp = (unsigned short*)(scw + 4352);// [16][72] bf16 (2304 B)
    unsigned short* PlWp = (unsigned short*)(scw + 6656);// [16][72] bf16 (2304 B)

    short8 aq0, aq1;   // Q A-fragments
    {
        const unsigned short* qp = Qb + (size_t)(row0 + j0) * DD + g * 8;
        aq0 = *(const short8*)qp;
        aq1 = *(const short8*)(qp + 32);
    }

    float m_r = -1e30f, l_r = 0.f, m_w = -1e30f, l_w = 0.f;
    float4v o_r[4], o_w[4];
    #pragma unroll
    for (int ns = 0; ns < 4; ns++) {
        o_r[ns] = (float4v){0.f, 0.f, 0.f, 0.f};
        o_w[ns] = (float4v){0.f, 0.f, 0.f, 0.f};
    }

    const size_t mrow = ((size_t)th * NN + row0 + lr) * NN;  // watt/mask row base

    const int kv_beg = w * (NN / 4);
    const int kv_end = kv_beg + (NN / 4);

    for (int kv0 = kv_beg; kv0 < kv_end; kv0 += 64) {
        // ---- watt/mask NT loads (consumed after QK^T + raw path) ----
        float4v wv4[4];
        int4v   mk4[4];
        {
            const float* wp = watt + mrow + kv0 + lc * 16;
            #pragma unroll
            for (int q = 0; q < 4; q++)
                wv4[q] = __builtin_nontemporal_load((const float4v*)&wp[q * 4]);
            load_mask_raw(maskp, mrow + kv0 + lc * 16, code, mk4);
        }

        // ---- QK^T, K-frags direct from L2: acc[c][i]=S[row0+4g+i][kv0+16c+j0]
        float4v acc[4];
        #pragma unroll
        for (int c = 0; c < 4; c++) {
            const unsigned short* kp = Kb + (size_t)(kv0 + c * 16 + j0) * DD + g * 8;
            short8 b0 = *(const short8*)kp;
            short8 b1 = *(const short8*)(kp + 32);
            float4v z = (float4v){0.f, 0.f, 0.f, 0.f};
            z = __builtin_amdgcn_mfma_f32_16x16x32_bf16(aq0, b0, z, 0, 0, 0);
            z = __builtin_amdgcn_mfma_f32_16x16x32_bf16(aq1, b1, z, 0, 0, 0);
            acc[c] = z;
        }
        // scatter S to LDS, re-read in remap arrangement (wave-local, in-order)
        #pragma unroll
        for (int c = 0; c < 4; c++)
            #pragma unroll
            for (int i = 0; i < 4; i++)
                Slp[(g * 4 + i) * 68 + c * 16 + j0] = acc[c][i];
        float4v s4[4];
        #pragma unroll
        for (int q = 0; q < 4; q++)
            s4[q] = *(const float4v*)&Slp[lr * 68 + lc * 16 + q * 4];

        // ---------------- raw path softmax ----------------
        {
            float tmax = -3.0e38f;
            #pragma unroll
            for (int q = 0; q < 4; q++)
                #pragma unroll
                for (int e = 0; e < 4; e++) tmax = fmaxf(tmax, s4[q][e]);
            tmax = fmaxf(tmax, __shfl_xor(tmax, 1, 64));
            tmax = fmaxf(tmax, __shfl_xor(tmax, 2, 64));
            float mn = fmaxf(m_r, tmax);
            float alpha = __expf(m_r - mn);
            m_r = mn;
            alignas(16) unsigned short pb[16];
            float tsum = 0.f;
            #pragma unroll
            for (int q = 0; q < 4; q++)
                #pragma unroll
                for (int e = 0; e < 4; e++) {
                    unsigned short b = f2bf(__expf(s4[q][e] - mn));
                    pb[q * 4 + e] = b; tsum += bf2f(b);
                }
            tsum += __shfl_xor(tsum, 1, 64);
            tsum += __shfl_xor(tsum, 2, 64);
            l_r = l_r * alpha + tsum;
            *(short8*)&PlRp[lr * 72 + lc * 16]     = *(const short8*)&pb[0];
            *(short8*)&PlRp[lr * 72 + lc * 16 + 8] = *(const short8*)&pb[8];
            float aR[4];
            #pragma unroll
            for (int i = 0; i < 4; i++) aR[i] = __shfl(alpha, (g * 4 + i) * 4, 64);
            #pragma unroll
            for (int ns = 0; ns < 4; ns++)
                #pragma unroll
                for (int i = 0; i < 4; i++) o_r[ns][i] *= aR[i];
        }

        // ---------------- weighted + masked path softmax ----------------
        {
            const unsigned pm = decode_pm(mk4, code);
            float sw[16];
            #pragma unroll
            for (int q = 0; q < 4; q++)
                #pragma unroll
                for (int e = 0; e < 4; e++) {
                    const int k = q * 4 + e;
                    sw[k] = ((pm >> k) & 1u) ? -1e30f : s4[q][e] * wv4[q][e];
                }
            float tmax = -3.0e38f;
            #pragma unroll
            for (int k = 0; k < 16; k++) tmax = fmaxf(tmax, sw[k]);
            tmax = fmaxf(tmax, __shfl_xor(tmax, 1, 64));
            tmax = fmaxf(tmax, __shfl_xor(tmax, 2, 64));
            float mn = fmaxf(m_w, tmax);
            float alpha = __expf(m_w - mn);
            m_w = mn;
            alignas(16) unsigned short pb[16];
            float tsum = 0.f;
            #pragma unroll
            for (int k = 0; k < 16; k++) {
                unsigned short b = f2bf(__expf(sw[k] - mn));
                pb[k] = b; tsum += bf2f(b);
            }
            tsum += __shfl_xor(tsum, 1, 64);
            tsum += __shfl_xor(tsum, 2, 64);
            l_w = l_w * alpha + tsum;
            *(short8*)&PlWp[lr * 72 + lc * 16]     = *(const short8*)&pb[0];
            *(short8*)&PlWp[lr * 72 + lc * 16 + 8] = *(const short8*)&pb[8];
            float aW[4];
            #pragma unroll
            for (int i = 0; i < 4; i++) aW[i] = __shfl(alpha, (g * 4 + i) * 4, 64);
            #pragma unroll
            for (int ns = 0; ns < 4; ns++)
                #pragma unroll
                for (int i = 0; i < 4; i++) o_w[ns][i] *= aW[i];
        }

        // ---- merged PV: each V fragment (from L2) feeds both paths ----
        #pragma unroll
        for (int ks2 = 0; ks2 < 2; ks2++) {
            short8 paR = *(const short8*)&PlRp[j0 * 72 + ks2 * 32 + g * 8];
            short8 paW = *(const short8*)&PlWp[j0 * 72 + ks2 * 32 + g * 8];
            #pragma unroll
            for (int ns = 0; ns < 4; ns++) {
                const unsigned short* vp =
                    Vtb + (size_t)(ns * 16 + j0) * NN + kv0 + ks2 * 32 + g * 8;
                short8 vb8 = *(const short8*)vp;
                o_r[ns] = __builtin_amdgcn_mfma_f32_16x16x32_bf16(paR, vb8, o_r[ns], 0, 0, 0);
                o_w[ns] = __builtin_amdgcn_mfma_f32_16x16x32_bf16(paW, vb8, o_w[ns], 0, 0, 0);
            }
        }
    }

    // =================== cross-wave flash merge epilogue ===================
    // Per-wave scratch (Sl region): o[16][64] f32 @0 (4096B), m[16] @4096,
    // l[16] @4160 (4224 <= 4352). Validated in R3.
    __syncthreads();   // B0: all PV scratch reads done

    // ---- path RAW ----
    {
        float* ov = (float*)scw;
        #pragma unroll
        for (int ns = 0; ns < 4; ns++)
            #pragma unroll
            for (int i = 0; i < 4; i++)
                ov[(g * 4 + i) * 64 + ns * 16 + j0] = o_r[ns][i];
        if (lc == 0) {
            *(float*)(scw + 4096 + lr * 4) = m_r;
            *(float*)(scw + 4160 + lr * 4) = l_r;
        }
    }
    __syncthreads();   // B1
    {
        const int r  = tid >> 4;          // 0..15
        const int c0 = (tid & 15) * 4;    // 0..60
        float mv[4];
        float M = -3.0e38f;
        #pragma unroll
        for (int u = 0; u < 4; u++) {
            mv[u] = *(const float*)(smem + u * SCR + 4096 + r * 4);
            M = fmaxf(M, mv[u]);
        }
        float L = 0.f;
        float4v a = (float4v){0.f, 0.f, 0.f, 0.f};
        #pragma unroll
        for (int u = 0; u < 4; u++) {
            const float f = __expf(mv[u] - M);
            L += f * *(const float*)(smem + u * SCR + 4160 + r * 4);
            float4v o4 = *(const float4v*)(smem + u * SCR + r * 256 + c0 * 4);
            #pragma unroll
            for (int e = 0; e < 4; e++) a[e] = fmaf(f, o4[e], a[e]);
        }
        const int row = row0 + r;
        const size_t ob = (((size_t)h * NN + row) * TT + t) * DD + c0;
        const float inv = 1.0f / L;
        float4v res = { a[0] * inv, a[1] * inv, a[2] * inv, a[3] * inv };
        *(float4v*)&out_raw[ob] = res;
    }
    __syncthreads();   // B2

    // ---- path WEIGHTED ----
    {
        float* ov = (float*)scw;
        #pragma unroll
        for (int ns = 0; ns < 4; ns++)
            #pragma unroll
            for (int i = 0; i < 4; i++)
                ov[(g * 4 + i) * 64 + ns * 16 + j0] = o_w[ns][i];
        if (lc == 0) {
            *(float*)(scw + 4096 + lr * 4) = m_w;
            *(float*)(scw + 4160 + lr * 4) = l_w;
        }
    }
    __syncthreads();   // B3
    {
        const int r  = tid >> 4;
        const int c0 = (tid & 15) * 4;
        float mv[4];
        float M = -3.0e38f;
        #pragma unroll
        for (int u = 0; u < 4; u++) {
            mv[u] = *(const float*)(smem + u * SCR + 4096 + r * 4);
            M = fmaxf(M, mv[u]);
        }
        float L = 0.f;
        float4v a = (float4v){0.f, 0.f, 0.f, 0.f};
        #pragma unroll
        for (int u = 0; u < 4; u++) {
            const float f = __expf(mv[u] - M);
            L += f * *(const float*)(smem + u * SCR + 4160 + r * 4);
            float4v o4 = *(const float4v*)(smem + u * SCR + r * 256 + c0 * 4);
            #pragma unroll
            for (int e = 0; e < 4; e++) a[e] = fmaf(f, o4[e], a[e]);
        }
        const int row = row0 + r;
        const size_t ob = (((size_t)h * NN + row) * TT + t) * DD + c0;
        const float inv = 1.0f / L;
        float4v res = { a[0] * inv, a[1] * inv, a[2] * inv, a[3] * inv };
        *(float4v*)&out[ob] = res;
    }
}

// ---------------------------------------------------------------------------
// Kernel 3: raw_att[t=3,h=0] slice — unchanged (R7-validated).
// ---------------------------------------------------------------------------
__global__ __launch_bounds__(256) void slice_b16_kernel(
    const unsigned short* __restrict__ q16, const unsigned short* __restrict__ k16,
    float* __restrict__ out_sl)
{
    const int tid = threadIdx.x;
    const int w = tid >> 6, lane = tid & 63;
    const int thsel = 12;  // t=3, h=0
    const unsigned short* Kb = k16 + (size_t)thsel * NN * DD;

    __shared__ float Tt[64][65];
    __shared__ float sr[4][NN];
    __shared__ float ql[4][64];

    ql[tid >> 6][tid & 63] =
        bf2f(q16[((size_t)thsel * NN + blockIdx.x * 4 + (tid >> 6))* DD + (tid & 63)]);
    __syncthreads();
    float qr[64];
    #pragma unroll
    for (int d = 0; d < 64; d++) qr[d] = ql[w][d];

    for (int kt = 0; kt < NN / 64; ++kt) {
        __syncthreads();
        const unsigned short* Ks = Kb + (size_t)kt * 64 * DD;
        #pragma unroll
        for (int u = 0; u < 16; ++u) {
            int e = u * 256 + tid;
            Tt[e >> 6][e & 63] = bf2f(Ks[e]);
        }
        __syncthreads();
        float a = 0.f;
        #pragma unroll
        for (int d = 0; d < 64; ++d)
            a = fmaf(qr[d], Tt[lane][d], a);
        sr[w][kt * 64 + lane] = a;
    }

    const int r = blockIdx.x * 4 + w;
    float mx = -3.0e38f;
    for (int m = lane; m < NN; m += 64) mx = fmaxf(mx, sr[w][m]);
    #pragma unroll
    for (int o = 1; o < 64; o <<= 1) mx = fmaxf(mx, __shfl_xor(mx, o, 64));
    float se = 0.f;
    for (int m = lane; m < NN; m += 64) se += __expf(sr[w][m] - mx);
    #pragma unroll
    for (int o = 1; o < 64; o <<= 1) se += __shfl_xor(se, o, 64);
    const float inv = 1.0f / se;
    for (int m = lane; m < NN; m += 64)
        out_sl[(size_t)r * NN + m] = __expf(sr[w][m] - mx) * inv;
}

// ---------------------------------------------------------------------------
extern "C" void kernel_launch(void* const* d_in, const int* in_sizes, int n_in,
                              void* d_out, int out_size, void* d_ws, size_t ws_size,
                              hipStream_t stream)
{
    (void)in_sizes; (void)n_in; (void)out_size; (void)ws_size;
    const float* x    = (const float*)d_in[0];
    const float* Wq   = (const float*)d_in[1];
    const float* bq   = (const float*)d_in[2];
    const float* Wk   = (const float*)d_in[3];
    const float* bk   = (const float*)d_in[4];
    const float* Wv   = (const float*)d_in[5];
    const float* bv   = (const float*)d_in[6];
    const float* watt = (const float*)d_in[7];
    const void*  mask = d_in[8];

    unsigned short* q16 = (unsigned short*)d_ws;              // 4 MB
    unsigned short* k16 = q16 + (size_t)THC * NN * DD;        // +4 MB
    unsigned short* v16 = k16 + (size_t)THC * NN * DD;        // +4 MB (12 MB)

    float* out     = (float*)d_out;
    float* out_raw = out + (size_t)NN * TT * HH * DD;
    float* out_sl  = out + 2 * (size_t)NN * TT * HH * DD;

    // v16t (4 MB) lives in the out_sl region as scratch: attn reads it, then
    // slice_b16_kernel fully overwrites out_sl afterwards.
    unsigned short* v16t = (unsigned short*)out_sl;

    proj_b16v_kernel<<<NN * TT / PROJ_ROWS, 256, 0, stream>>>(
        x, Wq, bq, Wk, bk, Wv, bv, q16, k16, v16);
    vtrans_kernel<<<THC * (NN / 64), 256, 0, stream>>>(v16, v16t);
    attn_mfma6_kernel<<<(NN / 16) * THC, 256, 0, stream>>>(
        q16, k16, v16t, watt, mask, out, out_raw);
    slice_b16_kernel<<<NN / 4, 256, 0, stream>>>(q16, k16, out_sl);
}

// Round 5
// 419.321 us; speedup vs baseline: 2.1956x; 1.0125x over previous
//
#include <hip/hip_runtime.h>
#include <hip/hip_bf16.h>

typedef __attribute__((ext_vector_type(8))) short short8;
typedef __attribute__((ext_vector_type(4))) float float4v;
typedef __attribute__((ext_vector_type(4))) int   int4v;

constexpr int NN = 2048;   // nodes
constexpr int TT = 4;      // time steps
constexpr int HH = 4;      // heads
constexpr int DD = 64;     // head dim
constexpr int THC = TT * HH;

__device__ __forceinline__ float bf2f(unsigned short u) {
    union { unsigned int i; float f; } c; c.i = ((unsigned int)u) << 16; return c.f;
}
__device__ __forceinline__ unsigned short f2bf(float f) {
    union { float f; unsigned int i; } c; c.f = f;
    unsigned int x = c.i;
    x += 0x7FFFu + ((x >> 16) & 1u);   // RNE
    return (unsigned short)(x >> 16);
}

// Mask dtype self-detect from first 1 KB (R6/R7-validated; pure fn of d_in).
// 0 = u8/bool, 1 = int32 0/1, 2 = f32, 3 = bf16.
__device__ __forceinline__ int mask_code_of(const unsigned int* mw) {
    int okInt = 1, okF32 = 1, okB = 1, anyLow = 0;
    for (int i = 0; i < 256; i++) {
        unsigned int w = mw[i];
        if (w > 1u) okInt = 0;
        if (!(w == 0u || w == 0x3F800000u)) okF32 = 0;
        unsigned int lo = w & 0xFFFFu, hi = w >> 16;
        if (!((lo == 0u || lo == 0x3F80u) && (hi == 0u || hi == 0x3F80u))) okB = 0;
        if (lo == 0x3F80u) anyLow = 1;
    }
    if (okInt) return 1;
    if (okF32 && !anyLow) return 2;
    if (okB) return 3;
    return 0;
}

// Vectorized nontemporal raw load of one 16-element mask slice, any dtype.
__device__ __forceinline__ void load_mask_raw(const void* p, size_t idx, int code,
                                              int4v mr[4]) {
    if (code == 1) {
        const int4v* mp = (const int4v*)((const int*)p + idx);
        #pragma unroll
        for (int q = 0; q < 4; q++) mr[q] = __builtin_nontemporal_load(mp + q);
    } else if (code == 2) {
        const int4v* mp = (const int4v*)((const float*)p + idx);
        #pragma unroll
        for (int q = 0; q < 4; q++) mr[q] = __builtin_nontemporal_load(mp + q);
    } else if (code == 3) {
        const int4v* mp = (const int4v*)((const unsigned short*)p + idx);
        mr[0] = __builtin_nontemporal_load(mp);
        mr[1] = __builtin_nontemporal_load(mp + 1);
    } else {  // u8/bool: 16 consecutive bytes, one dwordx4
        mr[0] = __builtin_nontemporal_load(
            (const int4v*)((const unsigned char*)p + idx));
    }
}
// Decode raw mask regs -> 16-bit predicate; bit k set iff element k is "true".
__device__ __forceinline__ unsigned decode_pm(const int4v mr[4], int code) {
    unsigned pm = 0u;
    if (code == 1) {
        #pragma unroll
        for (int q = 0; q < 4; q++)
            #pragma unroll
            for (int e = 0; e < 4; e++)
                if (mr[q][e] != 0) pm |= 1u << (q * 4 + e);
    } else if (code == 2) {
        #pragma unroll
        for (int q = 0; q < 4; q++)
            #pragma unroll
            for (int e = 0; e < 4; e++)
                if ((((unsigned)mr[q][e]) << 1) != 0u) pm |= 1u << (q * 4 + e);
    } else if (code == 3) {
        #pragma unroll
        for (int q = 0; q < 2; q++)
            #pragma unroll
            for (int e = 0; e < 4; e++) {
                unsigned w = (unsigned)mr[q][e];
                if (w & 0xFFFFu) pm |= 1u << (q * 8 + e * 2);
                if (w >> 16)     pm |= 1u << (q * 8 + e * 2 + 1);
            }
    } else {
        #pragma unroll
        for (int q = 0; q < 4; q++) {
            unsigned w = (unsigned)mr[0][q];
            #pragma unroll
            for (int b = 0; b < 4; b++)
                if ((w >> (8 * b)) & 0xFFu) pm |= 1u << (q * 4 + b);
        }
    }
    return pm;
}

// ---------------------------------------------------------------------------
// Kernel 1: projections, vectorized — unchanged (R6-validated FMA order).
// ---------------------------------------------------------------------------
constexpr int PROJ_ROWS = 8;
__global__ __launch_bounds__(256) void proj_b16v_kernel(
    const float* __restrict__ x,
    const float* __restrict__ Wq, const float* __restrict__ bq,
    const float* __restrict__ Wk, const float* __restrict__ bk,
    const float* __restrict__ Wv, const float* __restrict__ bv,
    unsigned short* __restrict__ q16, unsigned short* __restrict__ k16,
    unsigned short* __restrict__ v16)
{
    __shared__ float xl[PROJ_ROWS][64];
    const int tid = threadIdx.x;
    const int r0 = blockIdx.x * PROJ_ROWS;
    for (int i = tid; i < PROJ_ROWS * 64; i += 256)
        xl[i >> 6][i & 63] = x[(size_t)r0 * 64 + i];
    __syncthreads();

    const int c = tid;
    const int hh = c >> 6, dd = c & 63;
    const float* Ws[3] = { Wq, Wk, Wv };
    const float* bs[3] = { bq, bk, bv };
    unsigned short* os[3] = { q16, k16, v16 };

    #pragma unroll
    for (int m = 0; m < 3; m++) {
        float4v wr4[16];
        #pragma unroll
        for (int i = 0; i < 16; i++)
            wr4[i] = *(const float4v*)&Ws[m][(size_t)c * 64 + i * 4];
        const float bias = bs[m][c];
        #pragma unroll
        for (int rr = 0; rr < PROJ_ROWS; rr++) {
            float a = bias;
            #pragma unroll
            for (int i = 0; i < 16; i++) {
                a = fmaf(wr4[i][0], xl[rr][4*i+0], a);
                a = fmaf(wr4[i][1], xl[rr][4*i+1], a);
                a = fmaf(wr4[i][2], xl[rr][4*i+2], a);
                a = fmaf(wr4[i][3], xl[rr][4*i+3], a);
            }
            if (m == 0) a *= 0.125f;
            const int r = r0 + rr;
            const int n = r >> 2, t = r & 3;
            const int th = t * HH + hh;
            os[m][((size_t)th * NN + n) * DD + dd] = f2bf(a);
        }
    }
}

// ---------------------------------------------------------------------------
// Kernel 1b: one-time V transpose  v16[th][n][d] -> v16t[th][d][n].
// ---------------------------------------------------------------------------
__global__ __launch_bounds__(256) void vtrans_kernel(
    const unsigned short* __restrict__ v16, unsigned short* __restrict__ v16t)
{
    __shared__ unsigned int Tl[64][65];
    const int tid = threadIdx.x;
    const int th = blockIdx.x >> 5;           // 0..15
    const int n0 = (blockIdx.x & 31) * 64;    // 0..2047 step 64
    const unsigned short* src = v16 + ((size_t)th * NN + n0) * DD;
    {
        const int r = tid >> 2, c0 = (tid & 3) * 16;
        short8 a0 = *(const short8*)&src[(size_t)r * DD + c0];
        short8 a1 = *(const short8*)&src[(size_t)r * DD + c0 + 8];
        #pragma unroll
        for (int e = 0; e < 8; e++) {
            Tl[r][c0 + e]     = (unsigned short)a0[e];
            Tl[r][c0 + 8 + e] = (unsigned short)a1[e];
        }
    }
    __syncthreads();
    {
        const int dr = tid >> 2, c0 = (tid & 3) * 16;
        alignas(16) unsigned short tmp[16];
        #pragma unroll
        for (int j = 0; j < 16; j++) tmp[j] = (unsigned short)Tl[c0 + j][dr];
        unsigned short* dst = v16t + ((size_t)th * DD + dr) * NN + n0 + c0;
        *(short8*)&dst[0] = *(const short8*)&tmp[0];
        *(short8*)&dst[8] = *(const short8*)&tmp[8];
    }
}

// ---------------------------------------------------------------------------
// Kernel 2: MFMA flash attention v7 — KV-SPLIT x4, UNCONSTRAINED registers.
// R4 lesson: launch_bounds(256,4) => 128 unified regs = ~64 arch + 64 AGPR
// => ~148 MB spill (WRITE_SIZE 164 vs 16 MB ideal). Fix: no min-waves arg
// (R2's identical loop body compiled spill-free unconstrained), and a
// low-pressure epilogue: BOTH paths' o/m/l are dumped to the per-wave LDS
// scratch (dead after last PV) behind a SINGLE barrier, then merged with
// almost no register state live — removes the 32-accumulator live-range
// spike across 4 barriers that drove the spill.
// Block = one 16-row q-tile, 4 waves; wave w covers kv [w*512, w*512+512).
// Grid 2048 x 256. Expected: ~4 blocks/CU from regs (16 waves/CU), LDS
// 35.8 KB x 4 = 143 KB/CU fits. Loop math byte-identical to R7-validated.
// mfma_f32_16x16x32_bf16: A lane(row=l&15,k=(l>>4)*8+e),
// B lane(col=l&15,k=(l>>4)*8+e), D lane(col=l&15,row=(l>>4)*4+reg).
// ---------------------------------------------------------------------------
constexpr int SCR = 8960;   // per-wave scratch bytes: Sl 4352 | PlR 2304 | PlW 2304
__global__ __launch_bounds__(256) void attn_mfma7_kernel(
    const unsigned short* __restrict__ q16, const unsigned short* __restrict__ k16,
    const unsigned short* __restrict__ v16t,
    const float* __restrict__ watt, const void* __restrict__ maskp,
    float* __restrict__ out, float* __restrict__ out_raw)
{
    const int code = mask_code_of((const unsigned int*)maskp);
    const int tid  = threadIdx.x;
    const int w    = tid >> 6;          // wave 0..3 = KV quarter
    const int lane = tid & 63;
    const int g    = lane >> 4;         // MFMA 16-lane group
    const int j0   = lane & 15;
    const int lr   = lane >> 2;         // remap: row 0..15
    const int lc   = lane & 3;          // remap: col quarter 0..3

    const int gid = blockIdx.x;         // 0..2047
    const int th  = gid & 15;           // XCD x hosts th in {x, x+8}: L2-local
    const int bx  = gid >> 4;           // 0..127
    const int t = th >> 2, h = th & 3;
    const int row0 = bx * 16;

    const unsigned short* Qb  = q16  + (size_t)th * NN * DD;
    const unsigned short* Kb  = k16  + (size_t)th * NN * DD;
    const unsigned short* Vtb = v16t + (size_t)th * DD * NN;

    __shared__ __align__(16) char smem[4 * SCR];
    char* scw = smem + w * SCR;
    float*          Slp  = (float*)scw;                  // [16][68] f32 (4352 B)
    unsigned short* PlRp = (unsigned short*)(scw + 4352);// [16][72] bf16 (2304 B)
    unsigned short* PlWp = (unsigned short*)(scw + 6656);// [16][72] bf16 (2304 B)

    short8 aq0, aq1;   // Q A-fragments
    {
        const unsigned short* qp = Qb + (size_t)(row0 + j0) * DD + g * 8;
        aq0 = *(const short8*)qp;
        aq1 = *(const short8*)(qp + 32);
    }

    float m_r = -1e30f, l_r = 0.f, m_w = -1e30f, l_w = 0.f;
    float4v o_r[4], o_w[4];
    #pragma unroll
    for (int ns = 0; ns < 4; ns++) {
        o_r[ns] = (float4v){0.f, 0.f, 0.f, 0.f};
        o_w[ns] = (float4v){0.f, 0.f, 0.f, 0.f};
    }

    const size_t mrow = ((size_t)th * NN + row0 + lr) * NN;  // watt/mask row base

    const int kv_beg = w * (NN / 4);
    const int kv_end = kv_beg + (NN / 4);

    for (int kv0 = kv_beg; kv0 < kv_end; kv0 += 64) {
        // ---- watt/mask NT loads (consumed after QK^T + raw path) ----
        float4v wv4[4];
        int4v   mk4[4];
        {
            const float* wp = watt + mrow + kv0 + lc * 16;
            #pragma unroll
            for (int q = 0; q < 4; q++)
                wv4[q] = __builtin_nontemporal_load((const float4v*)&wp[q * 4]);
            load_mask_raw(maskp, mrow + kv0 + lc * 16, code, mk4);
        }

        // ---- QK^T, K-frags direct from L2: acc[c][i]=S[row0+4g+i][kv0+16c+j0]
        float4v acc[4];
        #pragma unroll
        for (int c = 0; c < 4; c++) {
            const unsigned short* kp = Kb + (size_t)(kv0 + c * 16 + j0) * DD + g * 8;
            short8 b0 = *(const short8*)kp;
            short8 b1 = *(const short8*)(kp + 32);
            float4v z = (float4v){0.f, 0.f, 0.f, 0.f};
            z = __builtin_amdgcn_mfma_f32_16x16x32_bf16(aq0, b0, z, 0, 0, 0);
            z = __builtin_amdgcn_mfma_f32_16x16x32_bf16(aq1, b1, z, 0, 0, 0);
            acc[c] = z;
        }
        // scatter S to LDS, re-read in remap arrangement (wave-local, in-order)
        #pragma unroll
        for (int c = 0; c < 4; c++)
            #pragma unroll
            for (int i = 0; i < 4; i++)
                Slp[(g * 4 + i) * 68 + c * 16 + j0] = acc[c][i];
        float4v s4[4];
        #pragma unroll
        for (int q = 0; q < 4; q++)
            s4[q] = *(const float4v*)&Slp[lr * 68 + lc * 16 + q * 4];

        // ---------------- raw path softmax ----------------
        {
            float tmax = -3.0e38f;
            #pragma unroll
            for (int q = 0; q < 4; q++)
                #pragma unroll
                for (int e = 0; e < 4; e++) tmax = fmaxf(tmax, s4[q][e]);
            tmax = fmaxf(tmax, __shfl_xor(tmax, 1, 64));
            tmax = fmaxf(tmax, __shfl_xor(tmax, 2, 64));
            float mn = fmaxf(m_r, tmax);
            float alpha = __expf(m_r - mn);
            m_r = mn;
            alignas(16) unsigned short pb[16];
            float tsum = 0.f;
            #pragma unroll
            for (int q = 0; q < 4; q++)
                #pragma unroll
                for (int e = 0; e < 4; e++) {
                    unsigned short b = f2bf(__expf(s4[q][e] - mn));
                    pb[q * 4 + e] = b; tsum += bf2f(b);
                }
            tsum += __shfl_xor(tsum, 1, 64);
            tsum += __shfl_xor(tsum, 2, 64);
            l_r = l_r * alpha + tsum;
            *(short8*)&PlRp[lr * 72 + lc * 16]     = *(const short8*)&pb[0];
            *(short8*)&PlRp[lr * 72 + lc * 16 + 8] = *(const short8*)&pb[8];
            float aR[4];
            #pragma unroll
            for (int i = 0; i < 4; i++) aR[i] = __shfl(alpha, (g * 4 + i) * 4, 64);
            #pragma unroll
            for (int ns = 0; ns < 4; ns++)
                #pragma unroll
                for (int i = 0; i < 4; i++) o_r[ns][i] *= aR[i];
        }

        // ---------------- weighted + masked path softmax ----------------
        {
            const unsigned pm = decode_pm(mk4, code);
            float sw[16];
            #pragma unroll
            for (int q = 0; q < 4; q++)
                #pragma unroll
                for (int e = 0; e < 4; e++) {
                    const int k = q * 4 + e;
                    sw[k] = ((pm >> k) & 1u) ? -1e30f : s4[q][e] * wv4[q][e];
                }
            float tmax = -3.0e38f;
            #pragma unroll
            for (int k = 0; k < 16; k++) tmax = fmaxf(tmax, sw[k]);
            tmax = fmaxf(tmax, __shfl_xor(tmax, 1, 64));
            tmax = fmaxf(tmax, __shfl_xor(tmax, 2, 64));
            float mn = fmaxf(m_w, tmax);
            float alpha = __expf(m_w - mn);
            m_w = mn;
            alignas(16) unsigned short pb[16];
            float tsum = 0.f;
            #pragma unroll
            for (int k = 0; k < 16; k++) {
                unsigned short b = f2bf(__expf(sw[k] - mn));
                pb[k] = b; tsum += bf2f(b);
            }
            tsum += __shfl_xor(tsum, 1, 64);
            tsum += __shfl_xor(tsum, 2, 64);
            l_w = l_w * alpha + tsum;
            *(short8*)&PlWp[lr * 72 + lc * 16]     = *(const short8*)&pb[0];
            *(short8*)&PlWp[lr * 72 + lc * 16 + 8] = *(const short8*)&pb[8];
            float aW[4];
            #pragma unroll
            for (int i = 0; i < 4; i++) aW[i] = __shfl(alpha, (g * 4 + i) * 4, 64);
            #pragma unroll
            for (int ns = 0; ns < 4; ns++)
                #pragma unroll
                for (int i = 0; i < 4; i++) o_w[ns][i] *= aW[i];
        }

        // ---- merged PV: each V fragment (from L2) feeds both paths ----
        #pragma unroll
        for (int ks2 = 0; ks2 < 2; ks2++) {
            short8 paR = *(const short8*)&PlRp[j0 * 72 + ks2 * 32 + g * 8];
            short8 paW = *(const short8*)&PlWp[j0 * 72 + ks2 * 32 + g * 8];
            #pragma unroll
            for (int ns = 0; ns < 4; ns++) {
                const unsigned short* vp =
                    Vtb + (size_t)(ns * 16 + j0) * NN + kv0 + ks2 * 32 + g * 8;
                short8 vb8 = *(const short8*)vp;
                o_r[ns] = __builtin_amdgcn_mfma_f32_16x16x32_bf16(paR, vb8, o_r[ns], 0, 0, 0);
                o_w[ns] = __builtin_amdgcn_mfma_f32_16x16x32_bf16(paW, vb8, o_w[ns], 0, 0, 0);
            }
        }
    }

    // ============ cross-wave flash merge epilogue (single barrier) =========
    // Per-wave scratch layout (regions dead after last PV, same-wave order):
    //   o_r[16][64] f32 @0      | m_r[16] @4096 | l_r[16] @4160
    //   o_w[16][64] f32 @4352   | m_w[16] @8448 | l_w[16] @8512   (8576<=8960)
    {
        float* ovR = (float*)scw;
        float* ovW = (float*)(scw + 4352);
        #pragma unroll
        for (int ns = 0; ns < 4; ns++)
            #pragma unroll
            for (int i = 0; i < 4; i++) {
                ovR[(g * 4 + i) * 64 + ns * 16 + j0] = o_r[ns][i];
                ovW[(g * 4 + i) * 64 + ns * 16 + j0] = o_w[ns][i];
            }
        if (lc == 0) {
            *(float*)(scw + 4096 + lr * 4) = m_r;
            *(float*)(scw + 4160 + lr * 4) = l_r;
            *(float*)(scw + 8448 + lr * 4) = m_w;
            *(float*)(scw + 8512 + lr * 4) = l_w;
        }
    }
    __syncthreads();
    {
        const int r  = tid >> 4;          // 0..15
        const int c0 = (tid & 15) * 4;    // 0..60
        const int row = row0 + r;
        const size_t ob = (((size_t)h * NN + row) * TT + t) * DD + c0;

        // ---- RAW merge ----
        {
            float mv[4];
            float M = -3.0e38f;
            #pragma unroll
            for (int u = 0; u < 4; u++) {
                mv[u] = *(const float*)(smem + u * SCR + 4096 + r * 4);
                M = fmaxf(M, mv[u]);
            }
            float L = 0.f;
            float4v a = (float4v){0.f, 0.f, 0.f, 0.f};
            #pragma unroll
            for (int u = 0; u < 4; u++) {
                const float f = __expf(mv[u] - M);
                L += f * *(const float*)(smem + u * SCR + 4160 + r * 4);
                float4v o4 = *(const float4v*)(smem + u * SCR + r * 256 + c0 * 4);
                #pragma unroll
                for (int e = 0; e < 4; e++) a[e] = fmaf(f, o4[e], a[e]);
            }
            const float inv = 1.0f / L;
            float4v res = { a[0] * inv, a[1] * inv, a[2] * inv, a[3] * inv };
            *(float4v*)&out_raw[ob] = res;
        }
        // ---- WEIGHTED merge ----
        {
            float mv[4];
            float M = -3.0e38f;
            #pragma unroll
            for (int u = 0; u < 4; u++) {
                mv[u] = *(const float*)(smem + u * SCR + 8448 + r * 4);
                M = fmaxf(M, mv[u]);
            }
            float L = 0.f;
            float4v a = (float4v){0.f, 0.f, 0.f, 0.f};
            #pragma unroll
            for (int u = 0; u < 4; u++) {
                const float f = __expf(mv[u] - M);
                L += f * *(const float*)(smem + u * SCR + 8512 + r * 4);
                float4v o4 = *(const float4v*)(smem + u * SCR + 4352 + r * 256 + c0 * 4);
                #pragma unroll
                for (int e = 0; e < 4; e++) a[e] = fmaf(f, o4[e], a[e]);
            }
            const float inv = 1.0f / L;
            float4v res = { a[0] * inv, a[1] * inv, a[2] * inv, a[3] * inv };
            *(float4v*)&out[ob] = res;
        }
    }
}

// ---------------------------------------------------------------------------
// Kernel 3: raw_att[t=3,h=0] slice — unchanged (R7-validated).
// ---------------------------------------------------------------------------
__global__ __launch_bounds__(256) void slice_b16_kernel(
    const unsigned short* __restrict__ q16, const unsigned short* __restrict__ k16,
    float* __restrict__ out_sl)
{
    const int tid = threadIdx.x;
    const int w = tid >> 6, lane = tid & 63;
    const int thsel = 12;  // t=3, h=0
    const unsigned short* Kb = k16 + (size_t)thsel * NN * DD;

    __shared__ float Tt[64][65];
    __shared__ float sr[4][NN];
    __shared__ float ql[4][64];

    ql[tid >> 6][tid & 63] =
        bf2f(q16[((size_t)thsel * NN + blockIdx.x * 4 + (tid >> 6))* DD + (tid & 63)]);
    __syncthreads();
    float qr[64];
    #pragma unroll
    for (int d = 0; d < 64; d++) qr[d] = ql[w][d];

    for (int kt = 0; kt < NN / 64; ++kt) {
        __syncthreads();
        const unsigned short* Ks = Kb + (size_t)kt * 64 * DD;
        #pragma unroll
        for (int u = 0; u < 16; ++u) {
            int e = u * 256 + tid;
            Tt[e >> 6][e & 63] = bf2f(Ks[e]);
        }
        __syncthreads();
        float a = 0.f;
        #pragma unroll
        for (int d = 0; d < 64; ++d)
            a = fmaf(qr[d], Tt[lane][d], a);
        sr[w][kt * 64 + lane] = a;
    }

    const int r = blockIdx.x * 4 + w;
    float mx = -3.0e38f;
    for (int m = lane; m < NN; m += 64) mx = fmaxf(mx, sr[w][m]);
    #pragma unroll
    for (int o = 1; o < 64; o <<= 1) mx = fmaxf(mx, __shfl_xor(mx, o, 64));
    float se = 0.f;
    for (int m = lane; m < NN; m += 64) se += __expf(sr[w][m] - mx);
    #pragma unroll
    for (int o = 1; o < 64; o <<= 1) se += __shfl_xor(se, o, 64);
    const float inv = 1.0f / se;
    for (int m = lane; m < NN; m += 64)
        out_sl[(size_t)r * NN + m] = __expf(sr[w][m] - mx) * inv;
}

// ---------------------------------------------------------------------------
extern "C" void kernel_launch(void* const* d_in, const int* in_sizes, int n_in,
                              void* d_out, int out_size, void* d_ws, size_t ws_size,
                              hipStream_t stream)
{
    (void)in_sizes; (void)n_in; (void)out_size; (void)ws_size;
    const float* x    = (const float*)d_in[0];
    const float* Wq   = (const float*)d_in[1];
    const float* bq   = (const float*)d_in[2];
    const float* Wk   = (const float*)d_in[3];
    const float* bk   = (const float*)d_in[4];
    const float* Wv   = (const float*)d_in[5];
    const float* bv   = (const float*)d_in[6];
    const float* watt = (const float*)d_in[7];
    const void*  mask = d_in[8];

    unsigned short* q16 = (unsigned short*)d_ws;              // 4 MB
    unsigned short* k16 = q16 + (size_t)THC * NN * DD;        // +4 MB
    unsigned short* v16 = k16 + (size_t)THC * NN * DD;        // +4 MB (12 MB)

    float* out     = (float*)d_out;
    float* out_raw = out + (size_t)NN * TT * HH * DD;
    float* out_sl  = out + 2 * (size_t)NN * TT * HH * DD;

    // v16t (4 MB) lives in the out_sl region as scratch: attn reads it, then
    // slice_b16_kernel fully overwrites out_sl afterwards.
    unsigned short* v16t = (unsigned short*)out_sl;

    proj_b16v_kernel<<<NN * TT / PROJ_ROWS, 256, 0, stream>>>(
        x, Wq, bq, Wk, bk, Wv, bv, q16, k16, v16);
    vtrans_kernel<<<THC * (NN / 64), 256, 0, stream>>>(v16, v16t);
    attn_mfma7_kernel<<<(NN / 16) * THC, 256, 0, stream>>>(
        q16, k16, v16t, watt, mask, out, out_raw);
    slice_b16_kernel<<<NN / 4, 256, 0, stream>>>(q16, k16, out_sl);
}

// Round 6
// 402.517 us; speedup vs baseline: 2.2873x; 1.0417x over previous
//
#include <hip/hip_runtime.h>
#include <hip/hip_bf16.h>

typedef __attribute__((ext_vector_type(8))) short short8;
typedef __attribute__((ext_vector_type(4))) float float4v;
typedef __attribute__((ext_vector_type(4))) int   int4v;

constexpr int NN = 2048;   // nodes
constexpr int TT = 4;      // time steps
constexpr int HH = 4;      // heads
constexpr int DD = 64;     // head dim
constexpr int THC = TT * HH;

__device__ __forceinline__ float bf2f(unsigned short u) {
    union { unsigned int i; float f; } c; c.i = ((unsigned int)u) << 16; return c.f;
}
__device__ __forceinline__ unsigned short f2bf(float f) {
    union { float f; unsigned int i; } c; c.f = f;
    unsigned int x = c.i;
    x += 0x7FFFu + ((x >> 16) & 1u);   // RNE
    return (unsigned short)(x >> 16);
}

// Mask dtype self-detect from first 1 KB (R6/R7-validated; pure fn of d_in).
// 0 = u8/bool, 1 = int32 0/1, 2 = f32, 3 = bf16.
__device__ __forceinline__ int mask_code_of(const unsigned int* mw) {
    int okInt = 1, okF32 = 1, okB = 1, anyLow = 0;
    for (int i = 0; i < 256; i++) {
        unsigned int w = mw[i];
        if (w > 1u) okInt = 0;
        if (!(w == 0u || w == 0x3F800000u)) okF32 = 0;
        unsigned int lo = w & 0xFFFFu, hi = w >> 16;
        if (!((lo == 0u || lo == 0x3F80u) && (hi == 0u || hi == 0x3F80u))) okB = 0;
        if (lo == 0x3F80u) anyLow = 1;
    }
    if (okInt) return 1;
    if (okF32 && !anyLow) return 2;
    if (okB) return 3;
    return 0;
}

// Vectorized nontemporal raw load of one 16-element mask slice, any dtype.
__device__ __forceinline__ void load_mask_raw(const void* p, size_t idx, int code,
                                              int4v mr[4]) {
    if (code == 1) {
        const int4v* mp = (const int4v*)((const int*)p + idx);
        #pragma unroll
        for (int q = 0; q < 4; q++) mr[q] = __builtin_nontemporal_load(mp + q);
    } else if (code == 2) {
        const int4v* mp = (const int4v*)((const float*)p + idx);
        #pragma unroll
        for (int q = 0; q < 4; q++) mr[q] = __builtin_nontemporal_load(mp + q);
    } else if (code == 3) {
        const int4v* mp = (const int4v*)((const unsigned short*)p + idx);
        mr[0] = __builtin_nontemporal_load(mp);
        mr[1] = __builtin_nontemporal_load(mp + 1);
    } else {  // u8/bool: 16 consecutive bytes, one dwordx4
        mr[0] = __builtin_nontemporal_load(
            (const int4v*)((const unsigned char*)p + idx));
    }
}
// Decode raw mask regs -> 16-bit predicate; bit k set iff element k is "true".
// Only reads mr[0] for code 0, mr[0..1] for code 3, mr[0..3] for codes 1/2.
__device__ __forceinline__ unsigned decode_pm(const int4v mr[4], int code) {
    unsigned pm = 0u;
    if (code == 1) {
        #pragma unroll
        for (int q = 0; q < 4; q++)
            #pragma unroll
            for (int e = 0; e < 4; e++)
                if (mr[q][e] != 0) pm |= 1u << (q * 4 + e);
    } else if (code == 2) {
        #pragma unroll
        for (int q = 0; q < 4; q++)
            #pragma unroll
            for (int e = 0; e < 4; e++)
                if ((((unsigned)mr[q][e]) << 1) != 0u) pm |= 1u << (q * 4 + e);
    } else if (code == 3) {
        #pragma unroll
        for (int q = 0; q < 2; q++)
            #pragma unroll
            for (int e = 0; e < 4; e++) {
                unsigned w = (unsigned)mr[q][e];
                if (w & 0xFFFFu) pm |= 1u << (q * 8 + e * 2);
                if (w >> 16)     pm |= 1u << (q * 8 + e * 2 + 1);
            }
    } else {
        #pragma unroll
        for (int q = 0; q < 4; q++) {
            unsigned w = (unsigned)mr[0][q];
            #pragma unroll
            for (int b = 0; b < 4; b++)
                if ((w >> (8 * b)) & 0xFFu) pm |= 1u << (q * 4 + b);
        }
    }
    return pm;
}

// ---------------------------------------------------------------------------
// Kernel 1: projections, vectorized — unchanged (R6-validated FMA order).
// ---------------------------------------------------------------------------
constexpr int PROJ_ROWS = 8;
__global__ __launch_bounds__(256) void proj_b16v_kernel(
    const float* __restrict__ x,
    const float* __restrict__ Wq, const float* __restrict__ bq,
    const float* __restrict__ Wk, const float* __restrict__ bk,
    const float* __restrict__ Wv, const float* __restrict__ bv,
    unsigned short* __restrict__ q16, unsigned short* __restrict__ k16,
    unsigned short* __restrict__ v16)
{
    __shared__ float xl[PROJ_ROWS][64];
    const int tid = threadIdx.x;
    const int r0 = blockIdx.x * PROJ_ROWS;
    for (int i = tid; i < PROJ_ROWS * 64; i += 256)
        xl[i >> 6][i & 63] = x[(size_t)r0 * 64 + i];
    __syncthreads();

    const int c = tid;
    const int hh = c >> 6, dd = c & 63;
    const float* Ws[3] = { Wq, Wk, Wv };
    const float* bs[3] = { bq, bk, bv };
    unsigned short* os[3] = { q16, k16, v16 };

    #pragma unroll
    for (int m = 0; m < 3; m++) {
        float4v wr4[16];
        #pragma unroll
        for (int i = 0; i < 16; i++)
            wr4[i] = *(const float4v*)&Ws[m][(size_t)c * 64 + i * 4];
        const float bias = bs[m][c];
        #pragma unroll
        for (int rr = 0; rr < PROJ_ROWS; rr++) {
            float a = bias;
            #pragma unroll
            for (int i = 0; i < 16; i++) {
                a = fmaf(wr4[i][0], xl[rr][4*i+0], a);
                a = fmaf(wr4[i][1], xl[rr][4*i+1], a);
                a = fmaf(wr4[i][2], xl[rr][4*i+2], a);
                a = fmaf(wr4[i][3], xl[rr][4*i+3], a);
            }
            if (m == 0) a *= 0.125f;
            const int r = r0 + rr;
            const int n = r >> 2, t = r & 3;
            const int th = t * HH + hh;
            os[m][((size_t)th * NN + n) * DD + dd] = f2bf(a);
        }
    }
}

// ---------------------------------------------------------------------------
// Kernel 1b: one-time V transpose  v16[th][n][d] -> v16t[th][d][n].
// ---------------------------------------------------------------------------
__global__ __launch_bounds__(256) void vtrans_kernel(
    const unsigned short* __restrict__ v16, unsigned short* __restrict__ v16t)
{
    __shared__ unsigned int Tl[64][65];
    const int tid = threadIdx.x;
    const int th = blockIdx.x >> 5;           // 0..15
    const int n0 = (blockIdx.x & 31) * 64;    // 0..2047 step 64
    const unsigned short* src = v16 + ((size_t)th * NN + n0) * DD;
    {
        const int r = tid >> 2, c0 = (tid & 3) * 16;
        short8 a0 = *(const short8*)&src[(size_t)r * DD + c0];
        short8 a1 = *(const short8*)&src[(size_t)r * DD + c0 + 8];
        #pragma unroll
        for (int e = 0; e < 8; e++) {
            Tl[r][c0 + e]     = (unsigned short)a0[e];
            Tl[r][c0 + 8 + e] = (unsigned short)a1[e];
        }
    }
    __syncthreads();
    {
        const int dr = tid >> 2, c0 = (tid & 3) * 16;
        alignas(16) unsigned short tmp[16];
        #pragma unroll
        for (int j = 0; j < 16; j++) tmp[j] = (unsigned short)Tl[c0 + j][dr];
        unsigned short* dst = v16t + ((size_t)th * DD + dr) * NN + n0 + c0;
        *(short8*)&dst[0] = *(const short8*)&tmp[0];
        *(short8*)&dst[8] = *(const short8*)&tmp[8];
    }
}

// ---------------------------------------------------------------------------
// Kernel 2: MFMA flash attention v8 — KV-SPLIT x4, 128-reg budget THAT FITS.
// R5 lesson: VGPR_Count=104 is ARCH only; +~64 AGPR (o/acc accumulators) put
// total at ~168 -> 2 blocks/CU (22.6% occ). Fix: launch_bounds(256,4) (128
// total cap) PLUS the pressure cuts R4 lacked:
//   (a) per-c QK^T: compute one acc quadrant, scatter to Sl immediately
//       (peak acc 16 -> 4 regs);
//   (b) mask diet: code 0 holds 1 int4v (4 regs), code 3 holds 2; codes 1/2
//       decode at load (16 regs transient, latency exposed only for those
//       codes); decode for 0/3 deferred past the raw path as before;
//   (c) R5's lean single-barrier epilogue (killed R4's spill site).
// Block = one 16-row q-tile, 4 waves; wave w covers kv [w*512, w*512+512).
// Grid 2048 x 256 = 8192 waves; target 4 blocks/CU = 16 waves/CU.
// LDS 35.8 KB/block x 4 = 143 KB/CU. Loop math byte-identical to validated.
// mfma_f32_16x16x32_bf16: A lane(row=l&15,k=(l>>4)*8+e),
// B lane(col=l&15,k=(l>>4)*8+e), D lane(col=l&15,row=(l>>4)*4+reg).
// ---------------------------------------------------------------------------
constexpr int SCR = 8960;   // per-wave scratch bytes: Sl 4352 | PlR 2304 | PlW 2304
__global__ __launch_bounds__(256, 4) void attn_mfma8_kernel(
    const unsigned short* __restrict__ q16, const unsigned short* __restrict__ k16,
    const unsigned short* __restrict__ v16t,
    const float* __restrict__ watt, const void* __restrict__ maskp,
    float* __restrict__ out, float* __restrict__ out_raw)
{
    const int code = mask_code_of((const unsigned int*)maskp);
    const int tid  = threadIdx.x;
    const int w    = tid >> 6;          // wave 0..3 = KV quarter
    const int lane = tid & 63;
    const int g    = lane >> 4;         // MFMA 16-lane group
    const int j0   = lane & 15;
    const int lr   = lane >> 2;         // remap: row 0..15
    const int lc   = lane & 3;          // remap: col quarter 0..3

    const int gid = blockIdx.x;         // 0..2047
    const int th  = gid & 15;           // XCD x hosts th in {x, x+8}: L2-local
    const int bx  = gid >> 4;           // 0..127
    const int t = th >> 2, h = th & 3;
    const int row0 = bx * 16;

    const unsigned short* Qb  = q16  + (size_t)th * NN * DD;
    const unsigned short* Kb  = k16  + (size_t)th * NN * DD;
    const unsigned short* Vtb = v16t + (size_t)th * DD * NN;

    __shared__ __align__(16) char smem[4 * SCR];
    char* scw = smem + w * SCR;
    float*          Slp  = (float*)scw;                  // [16][68] f32 (4352 B)
    unsigned short* PlRp = (unsigned short*)(scw + 4352);// [16][72] bf16 (2304 B)
    unsigned short* PlWp = (unsigned short*)(scw + 6656);// [16][72] bf16 (2304 B)

    short8 aq0, aq1;   // Q A-fragments
    {
        const unsigned short* qp = Qb + (size_t)(row0 + j0) * DD + g * 8;
        aq0 = *(const short8*)qp;
        aq1 = *(const short8*)(qp + 32);
    }

    float m_r = -1e30f, l_r = 0.f, m_w = -1e30f, l_w = 0.f;
    float4v o_r[4], o_w[4];
    #pragma unroll
    for (int ns = 0; ns < 4; ns++) {
        o_r[ns] = (float4v){0.f, 0.f, 0.f, 0.f};
        o_w[ns] = (float4v){0.f, 0.f, 0.f, 0.f};
    }

    const size_t mrow = ((size_t)th * NN + row0 + lr) * NN;  // watt/mask row base

    const int kv_beg = w * (NN / 4);
    const int kv_end = kv_beg + (NN / 4);

    for (int kv0 = kv_beg; kv0 < kv_end; kv0 += 64) {
        // ---- watt/mask NT loads (consumed after QK^T + raw path) ----
        float4v wv4[4];
        int4v   mh0 = {0, 0, 0, 0}, mh1 = {0, 0, 0, 0};  // raw hold (codes 0/3)
        unsigned pmPre = 0u;                             // decoded (codes 1/2)
        {
            const float* wp = watt + mrow + kv0 + lc * 16;
            #pragma unroll
            for (int q = 0; q < 4; q++)
                wv4[q] = __builtin_nontemporal_load((const float4v*)&wp[q * 4]);
            const size_t midx = mrow + kv0 + lc * 16;
            if (code == 0) {
                mh0 = __builtin_nontemporal_load(
                    (const int4v*)((const unsigned char*)maskp + midx));
            } else if (code == 3) {
                const int4v* mp = (const int4v*)((const unsigned short*)maskp + midx);
                mh0 = __builtin_nontemporal_load(mp);
                mh1 = __builtin_nontemporal_load(mp + 1);
            } else {
                int4v tr[4];
                load_mask_raw(maskp, midx, code, tr);
                pmPre = decode_pm(tr, code);   // 16 regs transient only
            }
        }

        // ---- QK^T per-quadrant with immediate scatter (acc peak = 4 regs) --
        #pragma unroll
        for (int c = 0; c < 4; c++) {
            const unsigned short* kp = Kb + (size_t)(kv0 + c * 16 + j0) * DD + g * 8;
            short8 b0 = *(const short8*)kp;
            short8 b1 = *(const short8*)(kp + 32);
            float4v z = (float4v){0.f, 0.f, 0.f, 0.f};
            z = __builtin_amdgcn_mfma_f32_16x16x32_bf16(aq0, b0, z, 0, 0, 0);
            z = __builtin_amdgcn_mfma_f32_16x16x32_bf16(aq1, b1, z, 0, 0, 0);
            #pragma unroll
            for (int i = 0; i < 4; i++)
                Slp[(g * 4 + i) * 68 + c * 16 + j0] = z[i];
        }
        // re-read in remap arrangement (wave-local, in-order)
        float4v s4[4];
        #pragma unroll
        for (int q = 0; q < 4; q++)
            s4[q] = *(const float4v*)&Slp[lr * 68 + lc * 16 + q * 4];

        // ---------------- raw path softmax ----------------
        {
            float tmax = -3.0e38f;
            #pragma unroll
            for (int q = 0; q < 4; q++)
                #pragma unroll
                for (int e = 0; e < 4; e++) tmax = fmaxf(tmax, s4[q][e]);
            tmax = fmaxf(tmax, __shfl_xor(tmax, 1, 64));
            tmax = fmaxf(tmax, __shfl_xor(tmax, 2, 64));
            float mn = fmaxf(m_r, tmax);
            float alpha = __expf(m_r - mn);
            m_r = mn;
            alignas(16) unsigned short pb[16];
            float tsum = 0.f;
            #pragma unroll
            for (int q = 0; q < 4; q++)
                #pragma unroll
                for (int e = 0; e < 4; e++) {
                    unsigned short b = f2bf(__expf(s4[q][e] - mn));
                    pb[q * 4 + e] = b; tsum += bf2f(b);
                }
            tsum += __shfl_xor(tsum, 1, 64);
            tsum += __shfl_xor(tsum, 2, 64);
            l_r = l_r * alpha + tsum;
            *(short8*)&PlRp[lr * 72 + lc * 16]     = *(const short8*)&pb[0];
            *(short8*)&PlRp[lr * 72 + lc * 16 + 8] = *(const short8*)&pb[8];
            float aR[4];
            #pragma unroll
            for (int i = 0; i < 4; i++) aR[i] = __shfl(alpha, (g * 4 + i) * 4, 64);
            #pragma unroll
            for (int ns = 0; ns < 4; ns++)
                #pragma unroll
                for (int i = 0; i < 4; i++) o_r[ns][i] *= aR[i];
        }

        // ---------------- weighted + masked path softmax ----------------
        {
            unsigned pm;
            if (code == 0) {
                int4v tr[4]; tr[0] = mh0;
                pm = decode_pm(tr, 0);
            } else if (code == 3) {
                int4v tr[4]; tr[0] = mh0; tr[1] = mh1;
                pm = decode_pm(tr, 3);
            } else {
                pm = pmPre;
            }
            float sw[16];
            #pragma unroll
            for (int q = 0; q < 4; q++)
                #pragma unroll
                for (int e = 0; e < 4; e++) {
                    const int k = q * 4 + e;
                    sw[k] = ((pm >> k) & 1u) ? -1e30f : s4[q][e] * wv4[q][e];
                }
            float tmax = -3.0e38f;
            #pragma unroll
            for (int k = 0; k < 16; k++) tmax = fmaxf(tmax, sw[k]);
            tmax = fmaxf(tmax, __shfl_xor(tmax, 1, 64));
            tmax = fmaxf(tmax, __shfl_xor(tmax, 2, 64));
            float mn = fmaxf(m_w, tmax);
            float alpha = __expf(m_w - mn);
            m_w = mn;
            alignas(16) unsigned short pb[16];
            float tsum = 0.f;
            #pragma unroll
            for (int k = 0; k < 16; k++) {
                unsigned short b = f2bf(__expf(sw[k] - mn));
                pb[k] = b; tsum += bf2f(b);
            }
            tsum += __shfl_xor(tsum, 1, 64);
            tsum += __shfl_xor(tsum, 2, 64);
            l_w = l_w * alpha + tsum;
            *(short8*)&PlWp[lr * 72 + lc * 16]     = *(const short8*)&pb[0];
            *(short8*)&PlWp[lr * 72 + lc * 16 + 8] = *(const short8*)&pb[8];
            float aW[4];
            #pragma unroll
            for (int i = 0; i < 4; i++) aW[i] = __shfl(alpha, (g * 4 + i) * 4, 64);
            #pragma unroll
            for (int ns = 0; ns < 4; ns++)
                #pragma unroll
                for (int i = 0; i < 4; i++) o_w[ns][i] *= aW[i];
        }

        // ---- merged PV: each V fragment (from L2) feeds both paths ----
        #pragma unroll
        for (int ks2 = 0; ks2 < 2; ks2++) {
            short8 paR = *(const short8*)&PlRp[j0 * 72 + ks2 * 32 + g * 8];
            short8 paW = *(const short8*)&PlWp[j0 * 72 + ks2 * 32 + g * 8];
            #pragma unroll
            for (int ns = 0; ns < 4; ns++) {
                const unsigned short* vp =
                    Vtb + (size_t)(ns * 16 + j0) * NN + kv0 + ks2 * 32 + g * 8;
                short8 vb8 = *(const short8*)vp;
                o_r[ns] = __builtin_amdgcn_mfma_f32_16x16x32_bf16(paR, vb8, o_r[ns], 0, 0, 0);
                o_w[ns] = __builtin_amdgcn_mfma_f32_16x16x32_bf16(paW, vb8, o_w[ns], 0, 0, 0);
            }
        }
    }

    // ============ cross-wave flash merge epilogue (single barrier) =========
    // Per-wave scratch layout (regions dead after last PV, same-wave order):
    //   o_r[16][64] f32 @0      | m_r[16] @4096 | l_r[16] @4160
    //   o_w[16][64] f32 @4352   | m_w[16] @8448 | l_w[16] @8512   (8576<=8960)
    {
        float* ovR = (float*)scw;
        float* ovW = (float*)(scw + 4352);
        #pragma unroll
        for (int ns = 0; ns < 4; ns++)
            #pragma unroll
            for (int i = 0; i < 4; i++) {
                ovR[(g * 4 + i) * 64 + ns * 16 + j0] = o_r[ns][i];
                ovW[(g * 4 + i) * 64 + ns * 16 + j0] = o_w[ns][i];
            }
        if (lc == 0) {
            *(float*)(scw + 4096 + lr * 4) = m_r;
            *(float*)(scw + 4160 + lr * 4) = l_r;
            *(float*)(scw + 8448 + lr * 4) = m_w;
            *(float*)(scw + 8512 + lr * 4) = l_w;
        }
    }
    __syncthreads();
    {
        const int r  = tid >> 4;          // 0..15
        const int c0 = (tid & 15) * 4;    // 0..60
        const int row = row0 + r;
        const size_t ob = (((size_t)h * NN + row) * TT + t) * DD + c0;

        // ---- RAW merge ----
        {
            float mv[4];
            float M = -3.0e38f;
            #pragma unroll
            for (int u = 0; u < 4; u++) {
                mv[u] = *(const float*)(smem + u * SCR + 4096 + r * 4);
                M = fmaxf(M, mv[u]);
            }
            float L = 0.f;
            float4v a = (float4v){0.f, 0.f, 0.f, 0.f};
            #pragma unroll
            for (int u = 0; u < 4; u++) {
                const float f = __expf(mv[u] - M);
                L += f * *(const float*)(smem + u * SCR + 4160 + r * 4);
                float4v o4 = *(const float4v*)(smem + u * SCR + r * 256 + c0 * 4);
                #pragma unroll
                for (int e = 0; e < 4; e++) a[e] = fmaf(f, o4[e], a[e]);
            }
            const float inv = 1.0f / L;
            float4v res = { a[0] * inv, a[1] * inv, a[2] * inv, a[3] * inv };
            *(float4v*)&out_raw[ob] = res;
        }
        // ---- WEIGHTED merge ----
        {
            float mv[4];
            float M = -3.0e38f;
            #pragma unroll
            for (int u = 0; u < 4; u++) {
                mv[u] = *(const float*)(smem + u * SCR + 8448 + r * 4);
                M = fmaxf(M, mv[u]);
            }
            float L = 0.f;
            float4v a = (float4v){0.f, 0.f, 0.f, 0.f};
            #pragma unroll
            for (int u = 0; u < 4; u++) {
                const float f = __expf(mv[u] - M);
                L += f * *(const float*)(smem + u * SCR + 8512 + r * 4);
                float4v o4 = *(const float4v*)(smem + u * SCR + 4352 + r * 256 + c0 * 4);
                #pragma unroll
                for (int e = 0; e < 4; e++) a[e] = fmaf(f, o4[e], a[e]);
            }
            const float inv = 1.0f / L;
            float4v res = { a[0] * inv, a[1] * inv, a[2] * inv, a[3] * inv };
            *(float4v*)&out[ob] = res;
        }
    }
}

// ---------------------------------------------------------------------------
// Kernel 3: raw_att[t=3,h=0] slice — unchanged (R7-validated).
// ---------------------------------------------------------------------------
__global__ __launch_bounds__(256) void slice_b16_kernel(
    const unsigned short* __restrict__ q16, const unsigned short* __restrict__ k16,
    float* __restrict__ out_sl)
{
    const int tid = threadIdx.x;
    const int w = tid >> 6, lane = tid & 63;
    const int thsel = 12;  // t=3, h=0
    const unsigned short* Kb = k16 + (size_t)thsel * NN * DD;

    __shared__ float Tt[64][65];
    __shared__ float sr[4][NN];
    __shared__ float ql[4][64];

    ql[tid >> 6][tid & 63] =
        bf2f(q16[((size_t)thsel * NN + blockIdx.x * 4 + (tid >> 6))* DD + (tid & 63)]);
    __syncthreads();
    float qr[64];
    #pragma unroll
    for (int d = 0; d < 64; d++) qr[d] = ql[w][d];

    for (int kt = 0; kt < NN / 64; ++kt) {
        __syncthreads();
        const unsigned short* Ks = Kb + (size_t)kt * 64 * DD;
        #pragma unroll
        for (int u = 0; u < 16; ++u) {
            int e = u * 256 + tid;
            Tt[e >> 6][e & 63] = bf2f(Ks[e]);
        }
        __syncthreads();
        float a = 0.f;
        #pragma unroll
        for (int d = 0; d < 64; ++d)
            a = fmaf(qr[d], Tt[lane][d], a);
        sr[w][kt * 64 + lane] = a;
    }

    const int r = blockIdx.x * 4 + w;
    float mx = -3.0e38f;
    for (int m = lane; m < NN; m += 64) mx = fmaxf(mx, sr[w][m]);
    #pragma unroll
    for (int o = 1; o < 64; o <<= 1) mx = fmaxf(mx, __shfl_xor(mx, o, 64));
    float se = 0.f;
    for (int m = lane; m < NN; m += 64) se += __expf(sr[w][m] - mx);
    #pragma unroll
    for (int o = 1; o < 64; o <<= 1) se += __shfl_xor(se, o, 64);
    const float inv = 1.0f / se;
    for (int m = lane; m < NN; m += 64)
        out_sl[(size_t)r * NN + m] = __expf(sr[w][m] - mx) * inv;
}

// ---------------------------------------------------------------------------
extern "C" void kernel_launch(void* const* d_in, const int* in_sizes, int n_in,
                              void* d_out, int out_size, void* d_ws, size_t ws_size,
                              hipStream_t stream)
{
    (void)in_sizes; (void)n_in; (void)out_size; (void)ws_size;
    const float* x    = (const float*)d_in[0];
    const float* Wq   = (const float*)d_in[1];
    const float* bq   = (const float*)d_in[2];
    const float* Wk   = (const float*)d_in[3];
    const float* bk   = (const float*)d_in[4];
    const float* Wv   = (const float*)d_in[5];
    const float* bv   = (const float*)d_in[6];
    const float* watt = (const float*)d_in[7];
    const void*  mask = d_in[8];

    unsigned short* q16 = (unsigned short*)d_ws;              // 4 MB
    unsigned short* k16 = q16 + (size_t)THC * NN * DD;        // +4 MB
    unsigned short* v16 = k16 + (size_t)THC * NN * DD;        // +4 MB (12 MB)

    float* out     = (float*)d_out;
    float* out_raw = out + (size_t)NN * TT * HH * DD;
    float* out_sl  = out + 2 * (size_t)NN * TT * HH * DD;

    // v16t (4 MB) lives in the out_sl region as scratch: attn reads it, then
    // slice_b16_kernel fully overwrites out_sl afterwards.
    unsigned short* v16t = (unsigned short*)out_sl;

    proj_b16v_kernel<<<NN * TT / PROJ_ROWS, 256, 0, stream>>>(
        x, Wq, bq, Wk, bk, Wv, bv, q16, k16, v16);
    vtrans_kernel<<<THC * (NN / 64), 256, 0, stream>>>(v16, v16t);
    attn_mfma8_kernel<<<(NN / 16) * THC, 256, 0, stream>>>(
        q16, k16, v16t, watt, mask, out, out_raw);
    slice_b16_kernel<<<NN / 4, 256, 0, stream>>>(q16, k16, out_sl);
}

// Round 7
// 397.688 us; speedup vs baseline: 2.3150x; 1.0121x over previous
//
#include <hip/hip_runtime.h>
#include <hip/hip_bf16.h>

typedef __attribute__((ext_vector_type(8))) short short8;
typedef __attribute__((ext_vector_type(4))) float float4v;
typedef __attribute__((ext_vector_type(4))) int   int4v;

constexpr int NN = 2048;   // nodes
constexpr int TT = 4;      // time steps
constexpr int HH = 4;      // heads
constexpr int DD = 64;     // head dim
constexpr int THC = TT * HH;

// Async global->LDS DMA (gfx950; size=16). LDS dest = wave-uniform base +
// lane*16; global src is per-lane. Counted in the issuing wave's vmcnt.
#define GL_LDS16(g, l) __builtin_amdgcn_global_load_lds(                     \
    (const __attribute__((address_space(1))) void*)(g),                      \
    (__attribute__((address_space(3))) void*)(l), 16, 0, 0)

__device__ __forceinline__ float bf2f(unsigned short u) {
    union { unsigned int i; float f; } c; c.i = ((unsigned int)u) << 16; return c.f;
}
__device__ __forceinline__ unsigned short f2bf(float f) {
    union { float f; unsigned int i; } c; c.f = f;
    unsigned int x = c.i;
    x += 0x7FFFu + ((x >> 16) & 1u);   // RNE
    return (unsigned short)(x >> 16);
}

// Mask dtype self-detect from first 1 KB (R6/R7-validated; pure fn of d_in).
// 0 = u8/bool, 1 = int32 0/1, 2 = f32, 3 = bf16.
__device__ __forceinline__ int mask_code_of(const unsigned int* mw) {
    int okInt = 1, okF32 = 1, okB = 1, anyLow = 0;
    for (int i = 0; i < 256; i++) {
        unsigned int w = mw[i];
        if (w > 1u) okInt = 0;
        if (!(w == 0u || w == 0x3F800000u)) okF32 = 0;
        unsigned int lo = w & 0xFFFFu, hi = w >> 16;
        if (!((lo == 0u || lo == 0x3F80u) && (hi == 0u || hi == 0x3F80u))) okB = 0;
        if (lo == 0x3F80u) anyLow = 1;
    }
    if (okInt) return 1;
    if (okF32 && !anyLow) return 2;
    if (okB) return 3;
    return 0;
}

// Plain (non-NT) vectorized raw load of one 16-element mask slice.
__device__ __forceinline__ void load_mask_raw(const void* p, size_t idx, int code,
                                              int4v mr[4]) {
    if (code == 1) {
        const int4v* mp = (const int4v*)((const int*)p + idx);
        #pragma unroll
        for (int q = 0; q < 4; q++) mr[q] = mp[q];
    } else if (code == 2) {
        const int4v* mp = (const int4v*)((const float*)p + idx);
        #pragma unroll
        for (int q = 0; q < 4; q++) mr[q] = mp[q];
    } else if (code == 3) {
        const int4v* mp = (const int4v*)((const unsigned short*)p + idx);
        mr[0] = mp[0]; mr[1] = mp[1];
    } else {
        mr[0] = *(const int4v*)((const unsigned char*)p + idx);
    }
}
// Decode raw mask regs -> 16-bit predicate; bit k set iff element k "true".
__device__ __forceinline__ unsigned decode_pm(const int4v mr[4], int code) {
    unsigned pm = 0u;
    if (code == 1) {
        #pragma unroll
        for (int q = 0; q < 4; q++)
            #pragma unroll
            for (int e = 0; e < 4; e++)
                if (mr[q][e] != 0) pm |= 1u << (q * 4 + e);
    } else if (code == 2) {
        #pragma unroll
        for (int q = 0; q < 4; q++)
            #pragma unroll
            for (int e = 0; e < 4; e++)
                if ((((unsigned)mr[q][e]) << 1) != 0u) pm |= 1u << (q * 4 + e);
    } else if (code == 3) {
        #pragma unroll
        for (int q = 0; q < 2; q++)
            #pragma unroll
            for (int e = 0; e < 4; e++) {
                unsigned w = (unsigned)mr[q][e];
                if (w & 0xFFFFu) pm |= 1u << (q * 8 + e * 2);
                if (w >> 16)     pm |= 1u << (q * 8 + e * 2 + 1);
            }
    } else {
        #pragma unroll
        for (int q = 0; q < 4; q++) {
            unsigned w = (unsigned)mr[0][q];
            #pragma unroll
            for (int b = 0; b < 4; b++)
                if ((w >> (8 * b)) & 0xFFu) pm |= 1u << (q * 4 + b);
        }
    }
    return pm;
}

// ---------------------------------------------------------------------------
// Kernel 1: projections, vectorized — unchanged (R6-validated FMA order).
// ---------------------------------------------------------------------------
constexpr int PROJ_ROWS = 8;
__global__ __launch_bounds__(256) void proj_b16v_kernel(
    const float* __restrict__ x,
    const float* __restrict__ Wq, const float* __restrict__ bq,
    const float* __restrict__ Wk, const float* __restrict__ bk,
    const float* __restrict__ Wv, const float* __restrict__ bv,
    unsigned short* __restrict__ q16, unsigned short* __restrict__ k16,
    unsigned short* __restrict__ v16)
{
    __shared__ float xl[PROJ_ROWS][64];
    const int tid = threadIdx.x;
    const int r0 = blockIdx.x * PROJ_ROWS;
    for (int i = tid; i < PROJ_ROWS * 64; i += 256)
        xl[i >> 6][i & 63] = x[(size_t)r0 * 64 + i];
    __syncthreads();

    const int c = tid;
    const int hh = c >> 6, dd = c & 63;
    const float* Ws[3] = { Wq, Wk, Wv };
    const float* bs[3] = { bq, bk, bv };
    unsigned short* os[3] = { q16, k16, v16 };

    #pragma unroll
    for (int m = 0; m < 3; m++) {
        float4v wr4[16];
        #pragma unroll
        for (int i = 0; i < 16; i++)
            wr4[i] = *(const float4v*)&Ws[m][(size_t)c * 64 + i * 4];
        const float bias = bs[m][c];
        #pragma unroll
        for (int rr = 0; rr < PROJ_ROWS; rr++) {
            float a = bias;
            #pragma unroll
            for (int i = 0; i < 16; i++) {
                a = fmaf(wr4[i][0], xl[rr][4*i+0], a);
                a = fmaf(wr4[i][1], xl[rr][4*i+1], a);
                a = fmaf(wr4[i][2], xl[rr][4*i+2], a);
                a = fmaf(wr4[i][3], xl[rr][4*i+3], a);
            }
            if (m == 0) a *= 0.125f;
            const int r = r0 + rr;
            const int n = r >> 2, t = r & 3;
            const int th = t * HH + hh;
            os[m][((size_t)th * NN + n) * DD + dd] = f2bf(a);
        }
    }
}

// ---------------------------------------------------------------------------
// Kernel 2: MFMA flash attention v9 — R0 structure + async watt/mask streams.
// R6 lesson: occupancy 22.6->44% gave +3% — the limiter is exposed HBM
// latency of in-loop watt/mask loads (~0.8 B/cyc/wave sustained), not TLP.
// Fixes:
//  * watt (all codes) + mask (code 0) streamed via global_load_lds DMA,
//    depth-2 double-buffer, issued ~2 tiles ahead — ~10 KB/wave in flight at
//    ZERO VGPR cost.
//  * K/V back to the R0-validated LDS staging (258 us structure): coalesced
//    loads, LDS gather — direct-L2 fragment gathers (R2-R6) regressed.
//  * RAW s_barrier + lgkmcnt(0) instead of __syncthreads: __syncthreads
//    emits vmcnt(0) and would drain the DMA pipeline at every barrier.
//  * NT flags dropped (correlated with BW drop 1054->860 GB/s).
//  * Sl aliases PlR/PlW per wave (R3-validated) with compiler fences: LDS =
//    Kl 10.2K + Vt 10.2K + union 5.1K*2 + wattS 16.4K + maskS 4K = 51.2 KB
//    -> 3 blocks/CU (6 waves/CU; trading TLP for MLP deliberately).
// Block = 32 q-rows x 2 waves (wave owns 16 rows), 1024 blocks, full KV
// sweep per wave (32 tiles of 64). Merged PV (R5/R6-validated), R0 epilogue.
// mfma_f32_16x16x32_bf16: A lane(row=l&15,k=(l>>4)*8+e),
// B lane(col=l&15,k=(l>>4)*8+e), D lane(col=l&15,row=(l>>4)*4+reg).
// ---------------------------------------------------------------------------
__global__ __launch_bounds__(128) void attn_mfma9_kernel(
    const unsigned short* __restrict__ q16, const unsigned short* __restrict__ k16,
    const unsigned short* __restrict__ v16,
    const float* __restrict__ watt, const void* __restrict__ maskp,
    float* __restrict__ out, float* __restrict__ out_raw)
{
    const int code = mask_code_of((const unsigned int*)maskp);
    const int tid  = threadIdx.x;
    const int wv   = tid >> 6;          // wave 0..1
    const int lane = tid & 63;
    const int g    = lane >> 4;         // MFMA 16-lane group
    const int j0   = lane & 15;
    const int lr   = lane >> 2;         // remap: row 0..15
    const int lc   = lane & 3;          // remap: col quarter 0..3

    const int gid = blockIdx.x;         // 0..1023
    const int th  = ((gid & 7) << 1) | ((gid >> 3) & 1);
    const int bx  = gid >> 4;           // 0..63
    const int t = th >> 2, h = th & 3;
    const int row0 = bx * 32 + wv * 16;

    const unsigned short* Qb = q16 + (size_t)th * NN * DD;
    const unsigned short* Kb = k16 + (size_t)th * NN * DD;
    const unsigned short* Vb = v16 + (size_t)th * NN * DD;

    __shared__ unsigned short Kl[64][80];        // K tile [kv][d] (shared)
    __shared__ unsigned short Vt[64][80];        // V^T tile [d][kv] (shared)
    __shared__ __align__(16) char SPu[2][5120];  // per-wave: Sl(16x68 f32) over
                                                 // PlR@0 / PlW@2560 (16x80 bf16)
    __shared__ __align__(16) char wattS[2][2][4096]; // [wave][buf] watt stream
    __shared__ __align__(16) char maskS[2][2][1024]; // [wave][buf] mask stream

    float*          Slp  = (float*)SPu[wv];
    unsigned short* PlRp = (unsigned short*)SPu[wv];
    unsigned short* PlWp = (unsigned short*)(SPu[wv] + 2560);

    const size_t mrow = ((size_t)th * NN + row0 + lr) * NN;  // watt/mask row base

    // ---- stream issue: 4 watt DMAs (+1 mask DMA for code 0) per tile ----
    auto issue_tile = [&](int kvt) {
        const int b = kvt & 1;
        const float* wsrc = watt + mrow + (size_t)kvt * 64 + lc * 16;
        char* wdst = &wattS[wv][b][0];
        #pragma unroll
        for (int q = 0; q < 4; q++)
            GL_LDS16(wsrc + q * 4, wdst + q * 1024);
        if (code == 0) {
            const unsigned char* msrc =
                (const unsigned char*)maskp + mrow + (size_t)kvt * 64 + lc * 16;
            GL_LDS16(msrc, &maskS[wv][b][0]);
        }
    };

    // prologue: get tiles 0 and 1 flying before anything else
    issue_tile(0);
    issue_tile(1);

    short8 aq0, aq1;   // Q A-fragments
    {
        const unsigned short* qp = Qb + (size_t)(row0 + j0) * DD + g * 8;
        aq0 = *(const short8*)qp;
        aq1 = *(const short8*)(qp + 32);
    }

    float m_r = -1e30f, l_r = 0.f, m_w = -1e30f, l_w = 0.f;
    float4v o_r[4], o_w[4];
    #pragma unroll
    for (int ns = 0; ns < 4; ns++) {
        o_r[ns] = (float4v){0.f, 0.f, 0.f, 0.f};
        o_w[ns] = (float4v){0.f, 0.f, 0.f, 0.f};
    }

    for (int it = 0; it < NN / 64; ++it) {
        const int kv0 = it * 64;
        const int buf = it & 1;

        // top barrier: all waves done reading Kl/Vt/Pl of prev tile.
        // RAW barrier (no vmcnt drain — DMAs stay in flight).
        asm volatile("s_waitcnt lgkmcnt(0)" ::: "memory");
        __builtin_amdgcn_s_barrier();

        // mask register path for codes 1/2/3 (issued early for latency)
        int4v mr0 = {0,0,0,0}, mr1 = {0,0,0,0};
        unsigned pmPre = 0u;
        if (code == 1 || code == 2) {
            int4v tr[4];
            load_mask_raw(maskp, mrow + kv0 + lc * 16, code, tr);
            pmPre = decode_pm(tr, code);
        } else if (code == 3) {
            const int4v* mp =
                (const int4v*)((const unsigned short*)maskp + mrow + kv0 + lc * 16);
            mr0 = mp[0]; mr1 = mp[1];
        }

        {   // stage K row-major and V^T (R0-validated; 128 threads, 64x64 tile)
            const int kr = tid >> 1;
            const int kc = (tid & 1) << 5;
            const unsigned short* ks = Kb + (size_t)(kv0 + kr) * DD + kc;
            short8 k0 = ((const short8*)ks)[0];
            short8 k1 = ((const short8*)ks)[1];
            short8 k2 = ((const short8*)ks)[2];
            short8 k3 = ((const short8*)ks)[3];
            const unsigned short* vs = Vb + (size_t)(kv0 + kr) * DD + kc;
            short8 v0 = ((const short8*)vs)[0];
            short8 v1 = ((const short8*)vs)[1];
            short8 v2 = ((const short8*)vs)[2];
            short8 v3 = ((const short8*)vs)[3];
            *(short8*)&Kl[kr][kc +  0] = k0;
            *(short8*)&Kl[kr][kc +  8] = k1;
            *(short8*)&Kl[kr][kc + 16] = k2;
            *(short8*)&Kl[kr][kc + 24] = k3;
            #pragma unroll
            for (int e = 0; e < 8; e++) {
                Vt[kc +      e][kr] = (unsigned short)v0[e];
                Vt[kc +  8 + e][kr] = (unsigned short)v1[e];
                Vt[kc + 16 + e][kr] = (unsigned short)v2[e];
                Vt[kc + 24 + e][kr] = (unsigned short)v3[e];
            }
        }
        asm volatile("s_waitcnt lgkmcnt(0)" ::: "memory");
        __builtin_amdgcn_s_barrier();

        // ---- QK^T from Kl: acc[c][i] = S[row0+4g+i][kv0+16c+j0] ----
        #pragma unroll
        for (int c = 0; c < 4; c++) {
            short8 b0 = *(const short8*)&Kl[c * 16 + j0][g * 8];
            short8 b1 = *(const short8*)&Kl[c * 16 + j0][32 + g * 8];
            float4v z = (float4v){0.f, 0.f, 0.f, 0.f};
            z = __builtin_amdgcn_mfma_f32_16x16x32_bf16(aq0, b0, z, 0, 0, 0);
            z = __builtin_amdgcn_mfma_f32_16x16x32_bf16(aq1, b1, z, 0, 0, 0);
            #pragma unroll
            for (int i = 0; i < 4; i++)
                Slp[(g * 4 + i) * 68 + c * 16 + j0] = z[i];
        }
        float4v s4[4];
        #pragma unroll
        for (int q = 0; q < 4; q++)
            s4[q] = *(const float4v*)&Slp[lr * 68 + lc * 16 + q * 4];
        // fence: s4 reads (float) must precede PlR/PlW writes (ushort) on the
        // same bytes — different TBAA types, same LDS region (R3-validated).
        asm volatile("" ::: "memory");

        // ---------------- raw path softmax ----------------
        {
            float tmax = -3.0e38f;
            #pragma unroll
            for (int q = 0; q < 4; q++)
                #pragma unroll
                for (int e = 0; e < 4; e++) tmax = fmaxf(tmax, s4[q][e]);
            tmax = fmaxf(tmax, __shfl_xor(tmax, 1, 64));
            tmax = fmaxf(tmax, __shfl_xor(tmax, 2, 64));
            float mn = fmaxf(m_r, tmax);
            float alpha = __expf(m_r - mn);
            m_r = mn;
            alignas(16) unsigned short pb[16];
            float tsum = 0.f;
            #pragma unroll
            for (int q = 0; q < 4; q++)
                #pragma unroll
                for (int e = 0; e < 4; e++) {
                    unsigned short b = f2bf(__expf(s4[q][e] - mn));
                    pb[q * 4 + e] = b; tsum += bf2f(b);
                }
            tsum += __shfl_xor(tsum, 1, 64);
            tsum += __shfl_xor(tsum, 2, 64);
            l_r = l_r * alpha + tsum;
            *(short8*)&PlRp[lr * 80 + lc * 16]     = *(const short8*)&pb[0];
            *(short8*)&PlRp[lr * 80 + lc * 16 + 8] = *(const short8*)&pb[8];
            float aR[4];
            #pragma unroll
            for (int i = 0; i < 4; i++) aR[i] = __shfl(alpha, (g * 4 + i) * 4, 64);
            #pragma unroll
            for (int ns = 0; ns < 4; ns++)
                #pragma unroll
                for (int i = 0; i < 4; i++) o_r[ns][i] *= aR[i];
        }

        // ---- wait for this tile's stream (DMA'd ~2 iterations ago) ----
        asm volatile("s_waitcnt vmcnt(0)" ::: "memory");
        __builtin_amdgcn_sched_barrier(0);

        float4v wv4[4];
        {
            const char* wsb = &wattS[wv][buf][0];
            #pragma unroll
            for (int q = 0; q < 4; q++)
                wv4[q] = *(const float4v*)(wsb + q * 1024 + (size_t)lane * 16);
        }
        unsigned pm;
        if (code == 0) {
            int4v tr[4];
            tr[0] = *(const int4v*)(&maskS[wv][buf][0] + (size_t)lane * 16);
            pm = decode_pm(tr, 0);
        } else if (code == 3) {
            int4v tr[4]; tr[0] = mr0; tr[1] = mr1;
            pm = decode_pm(tr, 3);
        } else {
            pm = pmPre;
        }

        // ---------------- weighted + masked path softmax ----------------
        {
            float sw[16];
            #pragma unroll
            for (int q = 0; q < 4; q++)
                #pragma unroll
                for (int e = 0; e < 4; e++) {
                    const int k = q * 4 + e;
                    sw[k] = ((pm >> k) & 1u) ? -1e30f : s4[q][e] * wv4[q][e];
                }
            float tmax = -3.0e38f;
            #pragma unroll
            for (int k = 0; k < 16; k++) tmax = fmaxf(tmax, sw[k]);
            tmax = fmaxf(tmax, __shfl_xor(tmax, 1, 64));
            tmax = fmaxf(tmax, __shfl_xor(tmax, 2, 64));
            float mn = fmaxf(m_w, tmax);
            float alpha = __expf(m_w - mn);
            m_w = mn;
            alignas(16) unsigned short pb[16];
            float tsum = 0.f;
            #pragma unroll
            for (int k = 0; k < 16; k++) {
                unsigned short b = f2bf(__expf(sw[k] - mn));
                pb[k] = b; tsum += bf2f(b);
            }
            tsum += __shfl_xor(tsum, 1, 64);
            tsum += __shfl_xor(tsum, 2, 64);
            l_w = l_w * alpha + tsum;
            *(short8*)&PlWp[lr * 80 + lc * 16]     = *(const short8*)&pb[0];
            *(short8*)&PlWp[lr * 80 + lc * 16 + 8] = *(const short8*)&pb[8];
            float aW[4];
            #pragma unroll
            for (int i = 0; i < 4; i++) aW[i] = __shfl(alpha, (g * 4 + i) * 4, 64);
            #pragma unroll
            for (int ns = 0; ns < 4; ns++)
                #pragma unroll
                for (int i = 0; i < 4; i++) o_w[ns][i] *= aW[i];
        }

        // re-issue this buffer for tile it+2 (stream regs fully consumed)
        if (it + 2 < NN / 64) issue_tile(it + 2);

        // ---- merged PV: each Vt fragment feeds both paths ----
        #pragma unroll
        for (int ks2 = 0; ks2 < 2; ks2++) {
            short8 paR = *(const short8*)&PlRp[j0 * 80 + ks2 * 32 + g * 8];
            short8 paW = *(const short8*)&PlWp[j0 * 80 + ks2 * 32 + g * 8];
            #pragma unroll
            for (int ns = 0; ns < 4; ns++) {
                short8 vb8 = *(const short8*)&Vt[ns * 16 + j0][ks2 * 32 + g * 8];
                o_r[ns] = __builtin_amdgcn_mfma_f32_16x16x32_bf16(paR, vb8, o_r[ns], 0, 0, 0);
                o_w[ns] = __builtin_amdgcn_mfma_f32_16x16x32_bf16(paW, vb8, o_w[ns], 0, 0, 0);
            }
        }
    }

    // epilogue (R0-validated): pull per-row l via shfl, normalize, store f32
    float lR[4], lW[4];
    #pragma unroll
    for (int i = 0; i < 4; i++) {
        lR[i] = __shfl(l_r, (g * 4 + i) * 4, 64);
        lW[i] = __shfl(l_w, (g * 4 + i) * 4, 64);
    }
    #pragma unroll
    for (int i = 0; i < 4; i++) {
        const int row = row0 + g * 4 + i;
        const size_t ob = (((size_t)h * NN + row) * TT + t) * DD;
        const float ir = 1.0f / lR[i];
        const float iw = 1.0f / lW[i];
        #pragma unroll
        for (int ns = 0; ns < 4; ns++) {
            out[ob + ns * 16 + j0]     = o_w[ns][i] * iw;
            out_raw[ob + ns * 16 + j0] = o_r[ns][i] * ir;
        }
    }
}

// ---------------------------------------------------------------------------
// Kernel 3: raw_att[t=3,h=0] slice — unchanged (R7-validated).
// ---------------------------------------------------------------------------
__global__ __launch_bounds__(256) void slice_b16_kernel(
    const unsigned short* __restrict__ q16, const unsigned short* __restrict__ k16,
    float* __restrict__ out_sl)
{
    const int tid = threadIdx.x;
    const int w = tid >> 6, lane = tid & 63;
    const int thsel = 12;  // t=3, h=0
    const unsigned short* Kb = k16 + (size_t)thsel * NN * DD;

    __shared__ float Tt[64][65];
    __shared__ float sr[4][NN];
    __shared__ float ql[4][64];

    ql[tid >> 6][tid & 63] =
        bf2f(q16[((size_t)thsel * NN + blockIdx.x * 4 + (tid >> 6))* DD + (tid & 63)]);
    __syncthreads();
    float qr[64];
    #pragma unroll
    for (int d = 0; d < 64; d++) qr[d] = ql[w][d];

    for (int kt = 0; kt < NN / 64; ++kt) {
        __syncthreads();
        const unsigned short* Ks = Kb + (size_t)kt * 64 * DD;
        #pragma unroll
        for (int u = 0; u < 16; ++u) {
            int e = u * 256 + tid;
            Tt[e >> 6][e & 63] = bf2f(Ks[e]);
        }
        __syncthreads();
        float a = 0.f;
        #pragma unroll
        for (int d = 0; d < 64; ++d)
            a = fmaf(qr[d], Tt[lane][d], a);
        sr[w][kt * 64 + lane] = a;
    }

    const int r = blockIdx.x * 4 + w;
    float mx = -3.0e38f;
    for (int m = lane; m < NN; m += 64) mx = fmaxf(mx, sr[w][m]);
    #pragma unroll
    for (int o = 1; o < 64; o <<= 1) mx = fmaxf(mx, __shfl_xor(mx, o, 64));
    float se = 0.f;
    for (int m = lane; m < NN; m += 64) se += __expf(sr[w][m] - mx);
    #pragma unroll
    for (int o = 1; o < 64; o <<= 1) se += __shfl_xor(se, o, 64);
    const float inv = 1.0f / se;
    for (int m = lane; m < NN; m += 64)
        out_sl[(size_t)r * NN + m] = __expf(sr[w][m] - mx) * inv;
}

// ---------------------------------------------------------------------------
extern "C" void kernel_launch(void* const* d_in, const int* in_sizes, int n_in,
                              void* d_out, int out_size, void* d_ws, size_t ws_size,
                              hipStream_t stream)
{
    (void)in_sizes; (void)n_in; (void)out_size; (void)ws_size;
    const float* x    = (const float*)d_in[0];
    const float* Wq   = (const float*)d_in[1];
    const float* bq   = (const float*)d_in[2];
    const float* Wk   = (const float*)d_in[3];
    const float* bk   = (const float*)d_in[4];
    const float* Wv   = (const float*)d_in[5];
    const float* bv   = (const float*)d_in[6];
    const float* watt = (const float*)d_in[7];
    const void*  mask = d_in[8];

    unsigned short* q16 = (unsigned short*)d_ws;              // 4 MB
    unsigned short* k16 = q16 + (size_t)THC * NN * DD;        // +4 MB
    unsigned short* v16 = k16 + (size_t)THC * NN * DD;        // +4 MB (12 MB)

    float* out     = (float*)d_out;
    float* out_raw = out + (size_t)NN * TT * HH * DD;
    float* out_sl  = out + 2 * (size_t)NN * TT * HH * DD;

    proj_b16v_kernel<<<NN * TT / PROJ_ROWS, 256, 0, stream>>>(
        x, Wq, bq, Wk, bk, Wv, bv, q16, k16, v16);
    attn_mfma9_kernel<<<(NN / 32) * THC, 128, 0, stream>>>(
        q16, k16, v16, watt, mask, out, out_raw);
    slice_b16_kernel<<<NN / 4, 256, 0, stream>>>(q16, k16, out_sl);
}

// Round 8
// 382.310 us; speedup vs baseline: 2.4081x; 1.0402x over previous
//
#include <hip/hip_runtime.h>
#include <hip/hip_bf16.h>

typedef __attribute__((ext_vector_type(8))) short short8;
typedef __attribute__((ext_vector_type(4))) float float4v;
typedef __attribute__((ext_vector_type(4))) int   int4v;

constexpr int NN = 2048;   // nodes
constexpr int TT = 4;      // time steps
constexpr int HH = 4;      // heads
constexpr int DD = 64;     // head dim
constexpr int THC = TT * HH;
constexpr int SUP = 256;   // watt/mask supertile span (kv)

__device__ __forceinline__ float bf2f(unsigned short u) {
    union { unsigned int i; float f; } c; c.i = ((unsigned int)u) << 16; return c.f;
}
__device__ __forceinline__ unsigned short f2bf(float f) {
    union { float f; unsigned int i; } c; c.f = f;
    unsigned int x = c.i;
    x += 0x7FFFu + ((x >> 16) & 1u);   // RNE
    return (unsigned short)(x >> 16);
}

// Mask dtype self-detect from first 1 KB (validated; pure fn of d_in).
// 0 = u8/bool, 1 = int32 0/1, 2 = f32, 3 = bf16.
__device__ __forceinline__ int mask_code_of(const unsigned int* mw) {
    int okInt = 1, okF32 = 1, okB = 1, anyLow = 0;
    for (int i = 0; i < 256; i++) {
        unsigned int w = mw[i];
        if (w > 1u) okInt = 0;
        if (!(w == 0u || w == 0x3F800000u)) okF32 = 0;
        unsigned int lo = w & 0xFFFFu, hi = w >> 16;
        if (!((lo == 0u || lo == 0x3F80u) && (hi == 0u || hi == 0x3F80u))) okB = 0;
        if (lo == 0x3F80u) anyLow = 1;
    }
    if (okInt) return 1;
    if (okF32 && !anyLow) return 2;
    if (okB) return 3;
    return 0;
}

// Plain vectorized raw load of one 16-element mask slice (codes 1/2/3 path).
__device__ __forceinline__ void load_mask_raw(const void* p, size_t idx, int code,
                                              int4v mr[4]) {
    if (code == 1) {
        const int4v* mp = (const int4v*)((const int*)p + idx);
        #pragma unroll
        for (int q = 0; q < 4; q++) mr[q] = mp[q];
    } else if (code == 2) {
        const int4v* mp = (const int4v*)((const float*)p + idx);
        #pragma unroll
        for (int q = 0; q < 4; q++) mr[q] = mp[q];
    } else if (code == 3) {
        const int4v* mp = (const int4v*)((const unsigned short*)p + idx);
        mr[0] = mp[0]; mr[1] = mp[1];
    } else {
        mr[0] = *(const int4v*)((const unsigned char*)p + idx);
    }
}
// Decode raw mask regs -> 16-bit predicate; bit k set iff element k "true".
__device__ __forceinline__ unsigned decode_pm(const int4v mr[4], int code) {
    unsigned pm = 0u;
    if (code == 1) {
        #pragma unroll
        for (int q = 0; q < 4; q++)
            #pragma unroll
            for (int e = 0; e < 4; e++)
                if (mr[q][e] != 0) pm |= 1u << (q * 4 + e);
    } else if (code == 2) {
        #pragma unroll
        for (int q = 0; q < 4; q++)
            #pragma unroll
            for (int e = 0; e < 4; e++)
                if ((((unsigned)mr[q][e]) << 1) != 0u) pm |= 1u << (q * 4 + e);
    } else if (code == 3) {
        #pragma unroll
        for (int q = 0; q < 2; q++)
            #pragma unroll
            for (int e = 0; e < 4; e++) {
                unsigned w = (unsigned)mr[q][e];
                if (w & 0xFFFFu) pm |= 1u << (q * 8 + e * 2);
                if (w >> 16)     pm |= 1u << (q * 8 + e * 2 + 1);
            }
    } else {
        #pragma unroll
        for (int q = 0; q < 4; q++) {
            unsigned w = (unsigned)mr[0][q];
            #pragma unroll
            for (int b = 0; b < 4; b++)
                if ((w >> (8 * b)) & 0xFFu) pm |= 1u << (q * 4 + b);
        }
    }
    return pm;
}

// ---------------------------------------------------------------------------
// Kernel 1: projections, vectorized — unchanged (validated FMA order).
// ---------------------------------------------------------------------------
constexpr int PROJ_ROWS = 8;
__global__ __launch_bounds__(256) void proj_b16v_kernel(
    const float* __restrict__ x,
    const float* __restrict__ Wq, const float* __restrict__ bq,
    const float* __restrict__ Wk, const float* __restrict__ bk,
    const float* __restrict__ Wv, const float* __restrict__ bv,
    unsigned short* __restrict__ q16, unsigned short* __restrict__ k16,
    unsigned short* __restrict__ v16)
{
    __shared__ float xl[PROJ_ROWS][64];
    const int tid = threadIdx.x;
    const int r0 = blockIdx.x * PROJ_ROWS;
    for (int i = tid; i < PROJ_ROWS * 64; i += 256)
        xl[i >> 6][i & 63] = x[(size_t)r0 * 64 + i];
    __syncthreads();

    const int c = tid;
    const int hh = c >> 6, dd = c & 63;
    const float* Ws[3] = { Wq, Wk, Wv };
    const float* bs[3] = { bq, bk, bv };
    unsigned short* os[3] = { q16, k16, v16 };

    #pragma unroll
    for (int m = 0; m < 3; m++) {
        float4v wr4[16];
        #pragma unroll
        for (int i = 0; i < 16; i++)
            wr4[i] = *(const float4v*)&Ws[m][(size_t)c * 64 + i * 4];
        const float bias = bs[m][c];
        #pragma unroll
        for (int rr = 0; rr < PROJ_ROWS; rr++) {
            float a = bias;
            #pragma unroll
            for (int i = 0; i < 16; i++) {
                a = fmaf(wr4[i][0], xl[rr][4*i+0], a);
                a = fmaf(wr4[i][1], xl[rr][4*i+1], a);
                a = fmaf(wr4[i][2], xl[rr][4*i+2], a);
                a = fmaf(wr4[i][3], xl[rr][4*i+3], a);
            }
            if (m == 0) a *= 0.125f;
            const int r = r0 + rr;
            const int n = r >> 2, t = r & 3;
            const int th = t * HH + hh;
            os[m][((size_t)th * NN + n) * DD + dd] = f2bf(a);
        }
    }
}

// ---------------------------------------------------------------------------
// Kernel 2: MFMA flash attention v10 — R0 structure + DRAM-burst supertiles.
// Diagnosis after R0-R7: HBM BW pinned at ~1 TB/s independent of occupancy
// and prefetch depth -> DRAM row-buffer thrash from ~30K interleaved 256-B
// watt streams. Fix: block-cooperative watt/mask staging in supertiles of
// 256 kv — each thread reads 256 B CONTIGUOUS (16 back-to-back dwordx4),
// 4 threads/row => 1 KB burst per row-visit, 8 visits per row total.
// T14 split: supertile loads issued into regs one iteration early (it%4==3),
// committed to LDS at the staging phase of it%4==0 (regs are free: LDS-bound
// at 2 blocks/CU). Weighted path reads watt/mask from LDS (pitch 268/272,
// <=4-way conflicts). K/V staging, softmax bodies, merged PV, aliased S/P
// scratch, epilogue: byte-identical to the validated R0/R7 code.
// Codes 1/2/3 masks keep the in-loop register path (not the perf case).
// LDS: Kl 10.2K + Vt 10.2K + SPu 10.2K + wattL 33.5K + maskL 8.5K = 72 KB
// -> 2 blocks/CU (4 waves/CU). Deliberate: trading occupancy for bursts.
// mfma_f32_16x16x32_bf16: A lane(row=l&15,k=(l>>4)*8+e),
// B lane(col=l&15,k=(l>>4)*8+e), D lane(col=l&15,row=(l>>4)*4+reg).
// ---------------------------------------------------------------------------
__global__ __launch_bounds__(128) void attn_mfma10_kernel(
    const unsigned short* __restrict__ q16, const unsigned short* __restrict__ k16,
    const unsigned short* __restrict__ v16,
    const float* __restrict__ watt, const void* __restrict__ maskp,
    float* __restrict__ out, float* __restrict__ out_raw)
{
    const int tid  = threadIdx.x;
    const int wv   = tid >> 6;          // wave 0..1
    const int lane = tid & 63;
    const int g    = lane >> 4;         // MFMA 16-lane group
    const int j0   = lane & 15;
    const int lr   = lane >> 2;         // remap: row 0..15
    const int lc   = lane & 3;          // remap: col quarter 0..3

    const int gid = blockIdx.x;         // 0..1023
    const int th  = ((gid & 7) << 1) | ((gid >> 3) & 1);
    const int bx  = gid >> 4;           // 0..63
    const int t = th >> 2, h = th & 3;
    const int row0b = bx * 32;          // block row base
    const int row0  = row0b + wv * 16;  // wave row base

    const unsigned short* Qb = q16 + (size_t)th * NN * DD;
    const unsigned short* Kb = k16 + (size_t)th * NN * DD;
    const unsigned short* Vb = v16 + (size_t)th * NN * DD;

    __shared__ unsigned short Kl[64][80];        // K tile [kv][d]
    __shared__ unsigned short Vt[64][80];        // V^T tile [d][kv]
    __shared__ __align__(16) char SPu[2][5120];  // per-wave: Sl(16x68 f32) over
                                                 // PlR@0 / PlW@2560 (16x80 bf16)
    __shared__ __align__(16) float wattL[32][268];        // supertile watt
    __shared__ __align__(16) unsigned char maskL[32][272];// supertile mask (u8)

    float*          Slp  = (float*)SPu[wv];
    unsigned short* PlRp = (unsigned short*)SPu[wv];
    unsigned short* PlWp = (unsigned short*)(SPu[wv] + 2560);

    // supertile staging map: 4 threads/row, 256 B contiguous per thread
    const int sr = tid >> 2;            // 0..31 block row
    const int sq = tid & 3;             // 64-f32 chunk
    const float* wattRow = watt +
        ((size_t)th * NN + row0b + sr) * NN + sq * 64;
    const unsigned char* maskRow =
        (const unsigned char*)maskp + ((size_t)th * NN + row0b + sr) * NN + sq * 64;

    float4v wpre[16];                   // in-flight supertile chunk (64 f32)
    int4v   mpre;                       // in-flight mask chunk (16 B)
    // issue: 16+1 independent contiguous dwordx4 loads (deep MLP, 1-KB bursts)
    auto issue_sup = [&](int s) {
        const float* ws = wattRow + (size_t)s * SUP;
        #pragma unroll
        for (int u = 0; u < 16; u++) wpre[u] = *(const float4v*)(ws + u * 4);
        mpre = *(const int4v*)(maskRow + (size_t)s * SUP);
    };
    auto commit_sup = [&]() {
        #pragma unroll
        for (int u = 0; u < 16; u++)
            *(float4v*)&wattL[sr][sq * 64 + u * 4] = wpre[u];
        *(int4v*)&maskL[sr][sq * 64] = mpre;
    };

    issue_sup(0);   // first: overlap with everything below

    const int code = mask_code_of((const unsigned int*)maskp);
    const size_t mrow = ((size_t)th * NN + row0 + lr) * NN;  // codes 1/2/3 path

    short8 aq0, aq1;   // Q A-fragments
    {
        const unsigned short* qp = Qb + (size_t)(row0 + j0) * DD + g * 8;
        aq0 = *(const short8*)qp;
        aq1 = *(const short8*)(qp + 32);
    }

    float m_r = -1e30f, l_r = 0.f, m_w = -1e30f, l_w = 0.f;
    float4v o_r[4], o_w[4];
    #pragma unroll
    for (int ns = 0; ns < 4; ns++) {
        o_r[ns] = (float4v){0.f, 0.f, 0.f, 0.f};
        o_w[ns] = (float4v){0.f, 0.f, 0.f, 0.f};
    }

    for (int it = 0; it < NN / 64; ++it) {
        const int kv0 = it * 64;
        const int sub = it & 3;

        __syncthreads();   // B1: all reads of Kl/Vt/Pl (and wattL if sub==0) done

        {   // stage K row-major and V^T (validated; 128 threads, 64x64 tile)
            const int kr = tid >> 1;
            const int kc = (tid & 1) << 5;
            const unsigned short* ks = Kb + (size_t)(kv0 + kr) * DD + kc;
            short8 k0 = ((const short8*)ks)[0];
            short8 k1 = ((const short8*)ks)[1];
            short8 k2 = ((const short8*)ks)[2];
            short8 k3 = ((const short8*)ks)[3];
            const unsigned short* vs = Vb + (size_t)(kv0 + kr) * DD + kc;
            short8 v0 = ((const short8*)vs)[0];
            short8 v1 = ((const short8*)vs)[1];
            short8 v2 = ((const short8*)vs)[2];
            short8 v3 = ((const short8*)vs)[3];
            *(short8*)&Kl[kr][kc +  0] = k0;
            *(short8*)&Kl[kr][kc +  8] = k1;
            *(short8*)&Kl[kr][kc + 16] = k2;
            *(short8*)&Kl[kr][kc + 24] = k3;
            #pragma unroll
            for (int e = 0; e < 8; e++) {
                Vt[kc +      e][kr] = (unsigned short)v0[e];
                Vt[kc +  8 + e][kr] = (unsigned short)v1[e];
                Vt[kc + 16 + e][kr] = (unsigned short)v2[e];
                Vt[kc + 24 + e][kr] = (unsigned short)v3[e];
            }
        }
        if (sub == 0) commit_sup();   // supertile it>>2 becomes visible at B2

        __syncthreads();   // B2

        // next supertile: issue loads early (full iteration of latency cover)
        if (sub == 3 && it + 1 < NN / 64) issue_sup((it + 1) >> 2);

        // codes 1/2/3 mask loads (register path, issued early)
        int4v mr0 = {0,0,0,0}, mr1 = {0,0,0,0};
        unsigned pmPre = 0u;
        if (code == 1 || code == 2) {
            int4v tr[4];
            load_mask_raw(maskp, mrow + kv0 + lc * 16, code, tr);
            pmPre = decode_pm(tr, code);
        } else if (code == 3) {
            const int4v* mp =
                (const int4v*)((const unsigned short*)maskp + mrow + kv0 + lc * 16);
            mr0 = mp[0]; mr1 = mp[1];
        }

        // ---- QK^T from Kl: acc[c][i] = S[row0+4g+i][kv0+16c+j0] ----
        #pragma unroll
        for (int c = 0; c < 4; c++) {
            short8 b0 = *(const short8*)&Kl[c * 16 + j0][g * 8];
            short8 b1 = *(const short8*)&Kl[c * 16 + j0][32 + g * 8];
            float4v z = (float4v){0.f, 0.f, 0.f, 0.f};
            z = __builtin_amdgcn_mfma_f32_16x16x32_bf16(aq0, b0, z, 0, 0, 0);
            z = __builtin_amdgcn_mfma_f32_16x16x32_bf16(aq1, b1, z, 0, 0, 0);
            #pragma unroll
            for (int i = 0; i < 4; i++)
                Slp[(g * 4 + i) * 68 + c * 16 + j0] = z[i];
        }
        float4v s4[4];
        #pragma unroll
        for (int q = 0; q < 4; q++)
            s4[q] = *(const float4v*)&Slp[lr * 68 + lc * 16 + q * 4];
        // fence: s4 float reads precede PlR/PlW ushort writes on same bytes
        asm volatile("" ::: "memory");

        // ---------------- raw path softmax (validated) ----------------
        {
            float tmax = -3.0e38f;
            #pragma unroll
            for (int q = 0; q < 4; q++)
                #pragma unroll
                for (int e = 0; e < 4; e++) tmax = fmaxf(tmax, s4[q][e]);
            tmax = fmaxf(tmax, __shfl_xor(tmax, 1, 64));
            tmax = fmaxf(tmax, __shfl_xor(tmax, 2, 64));
            float mn = fmaxf(m_r, tmax);
            float alpha = __expf(m_r - mn);
            m_r = mn;
            alignas(16) unsigned short pb[16];
            float tsum = 0.f;
            #pragma unroll
            for (int q = 0; q < 4; q++)
                #pragma unroll
                for (int e = 0; e < 4; e++) {
                    unsigned short b = f2bf(__expf(s4[q][e] - mn));
                    pb[q * 4 + e] = b; tsum += bf2f(b);
                }
            tsum += __shfl_xor(tsum, 1, 64);
            tsum += __shfl_xor(tsum, 2, 64);
            l_r = l_r * alpha + tsum;
            *(short8*)&PlRp[lr * 80 + lc * 16]     = *(const short8*)&pb[0];
            *(short8*)&PlRp[lr * 80 + lc * 16 + 8] = *(const short8*)&pb[8];
            float aR[4];
            #pragma unroll
            for (int i = 0; i < 4; i++) aR[i] = __shfl(alpha, (g * 4 + i) * 4, 64);
            #pragma unroll
            for (int ns = 0; ns < 4; ns++)
                #pragma unroll
                for (int i = 0; i < 4; i++) o_r[ns][i] *= aR[i];
        }

        // ---- watt/mask for this sub-tile from LDS supertile ----
        float4v wv4[4];
        {
            const float* wrow = &wattL[wv * 16 + lr][sub * 64 + lc * 16];
            #pragma unroll
            for (int q = 0; q < 4; q++) wv4[q] = *(const float4v*)(wrow + q * 4);
        }
        unsigned pm;
        if (code == 0) {
            int4v tr[4];
            tr[0] = *(const int4v*)&maskL[wv * 16 + lr][sub * 64 + lc * 16];
            pm = decode_pm(tr, 0);
        } else if (code == 3) {
            int4v tr[4]; tr[0] = mr0; tr[1] = mr1;
            pm = decode_pm(tr, 3);
        } else {
            pm = pmPre;
        }

        // ---------------- weighted + masked path softmax (validated) -------
        {
            float sw[16];
            #pragma unroll
            for (int q = 0; q < 4; q++)
                #pragma unroll
                for (int e = 0; e < 4; e++) {
                    const int k = q * 4 + e;
                    sw[k] = ((pm >> k) & 1u) ? -1e30f : s4[q][e] * wv4[q][e];
                }
            float tmax = -3.0e38f;
            #pragma unroll
            for (int k = 0; k < 16; k++) tmax = fmaxf(tmax, sw[k]);
            tmax = fmaxf(tmax, __shfl_xor(tmax, 1, 64));
            tmax = fmaxf(tmax, __shfl_xor(tmax, 2, 64));
            float mn = fmaxf(m_w, tmax);
            float alpha = __expf(m_w - mn);
            m_w = mn;
            alignas(16) unsigned short pb[16];
            float tsum = 0.f;
            #pragma unroll
            for (int k = 0; k < 16; k++) {
                unsigned short b = f2bf(__expf(sw[k] - mn));
                pb[k] = b; tsum += bf2f(b);
            }
            tsum += __shfl_xor(tsum, 1, 64);
            tsum += __shfl_xor(tsum, 2, 64);
            l_w = l_w * alpha + tsum;
            *(short8*)&PlWp[lr * 80 + lc * 16]     = *(const short8*)&pb[0];
            *(short8*)&PlWp[lr * 80 + lc * 16 + 8] = *(const short8*)&pb[8];
            float aW[4];
            #pragma unroll
            for (int i = 0; i < 4; i++) aW[i] = __shfl(alpha, (g * 4 + i) * 4, 64);
            #pragma unroll
            for (int ns = 0; ns < 4; ns++)
                #pragma unroll
                for (int i = 0; i < 4; i++) o_w[ns][i] *= aW[i];
        }

        // ---- merged PV: each Vt fragment feeds both paths (validated) ----
        #pragma unroll
        for (int ks2 = 0; ks2 < 2; ks2++) {
            short8 paR = *(const short8*)&PlRp[j0 * 80 + ks2 * 32 + g * 8];
            short8 paW = *(const short8*)&PlWp[j0 * 80 + ks2 * 32 + g * 8];
            #pragma unroll
            for (int ns = 0; ns < 4; ns++) {
                short8 vb8 = *(const short8*)&Vt[ns * 16 + j0][ks2 * 32 + g * 8];
                o_r[ns] = __builtin_amdgcn_mfma_f32_16x16x32_bf16(paR, vb8, o_r[ns], 0, 0, 0);
                o_w[ns] = __builtin_amdgcn_mfma_f32_16x16x32_bf16(paW, vb8, o_w[ns], 0, 0, 0);
            }
        }
    }

    // epilogue (validated): pull per-row l via shfl, normalize, store f32
    float lR[4], lW[4];
    #pragma unroll
    for (int i = 0; i < 4; i++) {
        lR[i] = __shfl(l_r, (g * 4 + i) * 4, 64);
        lW[i] = __shfl(l_w, (g * 4 + i) * 4, 64);
    }
    #pragma unroll
    for (int i = 0; i < 4; i++) {
        const int row = row0 + g * 4 + i;
        const size_t ob = (((size_t)h * NN + row) * TT + t) * DD;
        const float ir = 1.0f / lR[i];
        const float iw = 1.0f / lW[i];
        #pragma unroll
        for (int ns = 0; ns < 4; ns++) {
            out[ob + ns * 16 + j0]     = o_w[ns][i] * iw;
            out_raw[ob + ns * 16 + j0] = o_r[ns][i] * ir;
        }
    }
}

// ---------------------------------------------------------------------------
// Kernel 3: raw_att[t=3,h=0] slice — unchanged (validated).
// ---------------------------------------------------------------------------
__global__ __launch_bounds__(256) void slice_b16_kernel(
    const unsigned short* __restrict__ q16, const unsigned short* __restrict__ k16,
    float* __restrict__ out_sl)
{
    const int tid = threadIdx.x;
    const int w = tid >> 6, lane = tid & 63;
    const int thsel = 12;  // t=3, h=0
    const unsigned short* Kb = k16 + (size_t)thsel * NN * DD;

    __shared__ float Tt[64][65];
    __shared__ float sr[4][NN];
    __shared__ float ql[4][64];

    ql[tid >> 6][tid & 63] =
        bf2f(q16[((size_t)thsel * NN + blockIdx.x * 4 + (tid >> 6))* DD + (tid & 63)]);
    __syncthreads();
    float qr[64];
    #pragma unroll
    for (int d = 0; d < 64; d++) qr[d] = ql[w][d];

    for (int kt = 0; kt < NN / 64; ++kt) {
        __syncthreads();
        const unsigned short* Ks = Kb + (size_t)kt * 64 * DD;
        #pragma unroll
        for (int u = 0; u < 16; ++u) {
            int e = u * 256 + tid;
            Tt[e >> 6][e & 63] = bf2f(Ks[e]);
        }
        __syncthreads();
        float a = 0.f;
        #pragma unroll
        for (int d = 0; d < 64; ++d)
            a = fmaf(qr[d], Tt[lane][d], a);
        sr[w][kt * 64 + lane] = a;
    }

    const int r = blockIdx.x * 4 + w;
    float mx = -3.0e38f;
    for (int m = lane; m < NN; m += 64) mx = fmaxf(mx, sr[w][m]);
    #pragma unroll
    for (int o = 1; o < 64; o <<= 1) mx = fmaxf(mx, __shfl_xor(mx, o, 64));
    float se = 0.f;
    for (int m = lane; m < NN; m += 64) se += __expf(sr[w][m] - mx);
    #pragma unroll
    for (int o = 1; o < 64; o <<= 1) se += __shfl_xor(se, o, 64);
    const float inv = 1.0f / se;
    for (int m = lane; m < NN; m += 64)
        out_sl[(size_t)r * NN + m] = __expf(sr[w][m] - mx) * inv;
}

// ---------------------------------------------------------------------------
extern "C" void kernel_launch(void* const* d_in, const int* in_sizes, int n_in,
                              void* d_out, int out_size, void* d_ws, size_t ws_size,
                              hipStream_t stream)
{
    (void)in_sizes; (void)n_in; (void)out_size; (void)ws_size;
    const float* x    = (const float*)d_in[0];
    const float* Wq   = (const float*)d_in[1];
    const float* bq   = (const float*)d_in[2];
    const float* Wk   = (const float*)d_in[3];
    const float* bk   = (const float*)d_in[4];
    const float* Wv   = (const float*)d_in[5];
    const float* bv   = (const float*)d_in[6];
    const float* watt = (const float*)d_in[7];
    const void*  mask = d_in[8];

    unsigned short* q16 = (unsigned short*)d_ws;              // 4 MB
    unsigned short* k16 = q16 + (size_t)THC * NN * DD;        // +4 MB
    unsigned short* v16 = k16 + (size_t)THC * NN * DD;        // +4 MB (12 MB)

    float* out     = (float*)d_out;
    float* out_raw = out + (size_t)NN * TT * HH * DD;
    float* out_sl  = out + 2 * (size_t)NN * TT * HH * DD;

    proj_b16v_kernel<<<NN * TT / PROJ_ROWS, 256, 0, stream>>>(
        x, Wq, bq, Wk, bk, Wv, bv, q16, k16, v16);
    attn_mfma10_kernel<<<(NN / 32) * THC, 128, 0, stream>>>(
        q16, k16, v16, watt, mask, out, out_raw);
    slice_b16_kernel<<<NN / 4, 256, 0, stream>>>(q16, k16, out_sl);
}